// Round 1
// baseline (3110.753 us; speedup 1.0000x reference)
//
#include <hip/hip_runtime.h>

#define NN 10000
#define BB 8
#define MROWS 80000   // BB*NN

typedef float f32x4 __attribute__((ext_vector_type(4)));
typedef __bf16 bf16x8 __attribute__((ext_vector_type(8)));

typedef __attribute__((address_space(1))) void as1_void;
typedef __attribute__((address_space(3))) void as3_void;

static __device__ __forceinline__ void gl_lds16(const void* g, void* l){
  __builtin_amdgcn_global_load_lds((as1_void*)g, (as3_void*)l, 16, 0, 0);
}

static __device__ __forceinline__ unsigned short f2bf(float f){
  unsigned u = __float_as_uint(f);
  u = u + 0x7fffu + ((u >> 16) & 1u);
  return (unsigned short)(u >> 16);
}
static __device__ __forceinline__ float bf2f(unsigned short h){
  return __uint_as_float(((unsigned)h) << 16);
}
static __device__ __forceinline__ float bflo(unsigned v){ return __uint_as_float(v << 16); }
static __device__ __forceinline__ float bfhi(unsigned v){ return __uint_as_float(v & 0xffff0000u); }

// ---------------- CSR build ----------------
__global__ void k_count(const int* __restrict__ dst, int E, int* __restrict__ counts){
  int i = blockIdx.x * blockDim.x + threadIdx.x;
  if(i < E) atomicAdd(&counts[dst[i]], 1);
}

__global__ void k_scan(const int* __restrict__ counts, int* __restrict__ rp){
  __shared__ int buf[1024];
  __shared__ int carry;
  const int t = threadIdx.x;
  if(t == 0){ carry = 0; rp[0] = 0; }
  __syncthreads();
  for(int base = 0; base < NN; base += 1024){
    int v = (base + t < NN) ? counts[base + t] : 0;
    buf[t] = v;
    __syncthreads();
    for(int off = 1; off < 1024; off <<= 1){
      int x = (t >= off) ? buf[t - off] : 0;
      __syncthreads();
      buf[t] += x;
      __syncthreads();
    }
    if(base + t < NN) rp[base + t + 1] = carry + buf[t];
    __syncthreads();
    if(t == 0) carry += buf[1023];
    __syncthreads();
  }
}

__global__ void k_fill(const int* __restrict__ dst, int E, const int* __restrict__ rp,
                       int* __restrict__ cursor, int* __restrict__ ci){
  int i = blockIdx.x * blockDim.x + threadIdx.x;
  if(i < E){
    int d = dst[i];
    int p = rp[d] + atomicAdd(&cursor[d], 1);
    ci[p] = i;   // edge id, sorted deterministically afterwards
  }
}

__global__ void k_sort_rows(const int* __restrict__ rp, int* __restrict__ ci, float* __restrict__ vw,
                            const int* __restrict__ esrc, const float* __restrict__ ew){
  const int n = blockIdx.x * blockDim.x + threadIdx.x;
  if(n >= NN) return;
  const int s = rp[n], e = rp[n + 1];
  for(int i = s; i < e - 1; ++i){           // selection sort by edge id (unique) -> deterministic
    int mj = i, mv = ci[i];
    for(int j = i + 1; j < e; ++j){
      int v = ci[j];
      if(v < mv){ mv = v; mj = j; }
    }
    ci[mj] = ci[i]; ci[i] = mv;
  }
  for(int p = s; p < e; ++p){
    int eid = ci[p];
    ci[p] = esrc[eid];
    vw[p] = ew[eid];
  }
}

// ---------------- f32 -> bf16 hi/lo split ----------------
__global__ void k_split(const float4* __restrict__ in, ushort4* __restrict__ hi,
                        ushort4* __restrict__ lo, int n4){
  int i = blockIdx.x * blockDim.x + threadIdx.x;
  if(i >= n4) return;
  float4 v = in[i];
  ushort4 h, l;
  h.x = f2bf(v.x); l.x = f2bf(v.x - bf2f(h.x));
  h.y = f2bf(v.y); l.y = f2bf(v.y - bf2f(h.y));
  h.z = f2bf(v.z); l.z = f2bf(v.z - bf2f(h.z));
  h.w = f2bf(v.w); l.w = f2bf(v.w - bf2f(h.w));
  hi[i] = h; lo[i] = l;
}

// Pack weights transposed: Wt[c][k] = W[k][c], hi/lo split.
// layout: [0, 512*512): layer0 (K=512, cols 0..255 = W_in, 256..511 = LW_in)
//         then 12 x [512][256] for W_blk/LW_blk
__global__ void k_pack_w(const float* __restrict__ Wi, const float* __restrict__ LWi,
                         const float* __restrict__ Wb, const float* __restrict__ LWb,
                         unsigned short* __restrict__ dh, unsigned short* __restrict__ dl){
  const int T0 = 512 * 512;
  const int TOT = T0 + 12 * 512 * 256;
  int i = blockIdx.x * blockDim.x + threadIdx.x;
  if(i >= TOT) return;
  float v;
  if(i < T0){
    int c = i >> 9, k = i & 511;
    v = (c < 256) ? Wi[k * 256 + c] : LWi[k * 256 + (c - 256)];
  } else {
    int j = i - T0;
    int li = j >> 17;          // 512*256 = 2^17
    int r = j & 131071;
    int c = r >> 8, k = r & 255;
    const float* src = (c < 256) ? (Wb + (size_t)li * 65536) : (LWb + (size_t)li * 65536);
    v = src[k * 256 + (c & 255)];
  }
  unsigned short h = f2bf(v);
  dh[i] = h;
  dl[i] = f2bf(v - bf2f(h));
}

// ---------------- dual GEMM: Sup(cols 0..255, bf16) / Loc(cols 256..511, f32) ----------------
// A: [80000, K] bf16 hi/lo,  Bt: [512, K] bf16 hi/lo (row = output col)
__global__ __launch_bounds__(256) void k_gemm_dual(
    const unsigned short* __restrict__ Ahi, const unsigned short* __restrict__ Alo,
    const unsigned short* __restrict__ Bhi, const unsigned short* __restrict__ Blo,
    unsigned short* __restrict__ Sup, float* __restrict__ Loc, int K)
{
  __shared__ unsigned short As[2][128 * 32];  // [hi/lo][128 rows x 32 k]
  __shared__ unsigned short Bs[2][128 * 32];
  const int t = threadIdx.x;
  const int m0 = blockIdx.x << 7;
  const int by = blockIdx.y;          // 0..3 ; 0,1 -> Sup cols, 2,3 -> Loc cols
  const int n0 = by << 7;
  const int lane = t & 63, wv = t >> 6;
  const int wm = (wv >> 1) << 6, wn = (wv & 1) << 6;
  const int rA = lane & 15, g = lane >> 4;
  f32x4 acc[4][4] = {};
  const int nsteps = K >> 5;

  for(int s = 0; s < nsteps; ++s){
    const size_t kb = (size_t)s * 64;   // byte offset along K
    #pragma unroll
    for(int p = 0; p < 2; ++p){
      const int off = p * 4096 + t * 16;     // byte offset within 8KB tile
      const int row = off >> 6, cb = off & 63;
      const size_t ga = (size_t)(m0 + row) * K * 2 + kb + cb;
      const size_t gb = (size_t)(n0 + row) * K * 2 + kb + cb;
      char* la = (char*)(&As[0][0]) + p * 4096 + (wv << 10);
      char* lb = (char*)(&Bs[0][0]) + p * 4096 + (wv << 10);
      gl_lds16((const char*)Ahi + ga, la);
      gl_lds16((const char*)Alo + ga, la + 8192);
      gl_lds16((const char*)Bhi + gb, lb);
      gl_lds16((const char*)Blo + gb, lb + 8192);
    }
    __syncthreads();
    bf16x8 ah[4], al[4], bh[4], bl[4];
    #pragma unroll
    for(int mi = 0; mi < 4; ++mi){
      const char* pa = (const char*)(&As[0][0]) + ((wm + mi * 16 + rA) << 6) + (g << 4);
      ah[mi] = *(const bf16x8*)pa;
      al[mi] = *(const bf16x8*)(pa + 8192);
    }
    #pragma unroll
    for(int ni = 0; ni < 4; ++ni){
      const char* pb = (const char*)(&Bs[0][0]) + ((wn + ni * 16 + rA) << 6) + (g << 4);
      bh[ni] = *(const bf16x8*)pb;
      bl[ni] = *(const bf16x8*)(pb + 8192);
    }
    #pragma unroll
    for(int mi = 0; mi < 4; ++mi){
      #pragma unroll
      for(int ni = 0; ni < 4; ++ni){
        f32x4 c = acc[mi][ni];
        c = __builtin_amdgcn_mfma_f32_16x16x32_bf16(al[mi], bh[ni], c, 0, 0, 0);
        c = __builtin_amdgcn_mfma_f32_16x16x32_bf16(ah[mi], bl[ni], c, 0, 0, 0);
        c = __builtin_amdgcn_mfma_f32_16x16x32_bf16(ah[mi], bh[ni], c, 0, 0, 0);
        acc[mi][ni] = c;
      }
    }
    __syncthreads();
  }

  const int colb = ((by & 1) << 7) + wn + rA;
  #pragma unroll
  for(int mi = 0; mi < 4; ++mi){
    const int rowb = m0 + wm + mi * 16 + g * 4;
    #pragma unroll
    for(int ni = 0; ni < 4; ++ni){
      const int col = colb + ni * 16;
      #pragma unroll
      for(int r = 0; r < 4; ++r){
        if(by < 2) Sup[(size_t)(rowb + r) * 256 + col] = f2bf(acc[mi][ni][r]);
        else       Loc[(size_t)(rowb + r) * 256 + col] = acc[mi][ni][r];
      }
    }
  }
}

// ---------------- aggregation + local + bias (+residual), hi/lo split output ----------------
// mode 0: Hnext only; mode 1: also carrier = t; mode 2: carrier = (carrier + t)*0.5, Hnext = bf16 of it
__global__ __launch_bounds__(256) void k_agg(
    const unsigned short* __restrict__ Sup, const float* __restrict__ Loc,
    const float* __restrict__ bias,
    const int* __restrict__ rp, const int* __restrict__ ci, const float* __restrict__ vw,
    unsigned short* __restrict__ Hhi, unsigned short* __restrict__ Hlo,
    float* __restrict__ carrier, const int mode)
{
  const int n = blockIdx.x;
  const int t = threadIdx.x;
  const int b = t >> 5;
  const int d0 = (t & 31) << 3;
  const size_t rowbase = ((size_t)b * NN + n) * 256 + d0;
  float a[8];
  {
    float4 l0 = *(const float4*)(Loc + rowbase);
    float4 l1 = *(const float4*)(Loc + rowbase + 4);
    float4 q0 = *(const float4*)(bias + d0);
    float4 q1 = *(const float4*)(bias + d0 + 4);
    a[0] = l0.x + q0.x; a[1] = l0.y + q0.y; a[2] = l0.z + q0.z; a[3] = l0.w + q0.w;
    a[4] = l1.x + q1.x; a[5] = l1.y + q1.y; a[6] = l1.z + q1.z; a[7] = l1.w + q1.w;
  }
  const int s = rp[n], e = rp[n + 1];
  const size_t bb = (size_t)b * NN * 256 + d0;
  for(int i = s; i < e; ++i){
    const int src = ci[i];
    const float w = vw[i];
    const uint4 sv = *(const uint4*)(Sup + bb + (size_t)src * 256);
    a[0] = fmaf(w, bflo(sv.x), a[0]);
    a[1] = fmaf(w, bfhi(sv.x), a[1]);
    a[2] = fmaf(w, bflo(sv.y), a[2]);
    a[3] = fmaf(w, bfhi(sv.y), a[3]);
    a[4] = fmaf(w, bflo(sv.z), a[4]);
    a[5] = fmaf(w, bfhi(sv.z), a[5]);
    a[6] = fmaf(w, bflo(sv.w), a[6]);
    a[7] = fmaf(w, bfhi(sv.w), a[7]);
  }
  if(mode == 2){
    float4 c0 = *(const float4*)(carrier + rowbase);
    float4 c1 = *(const float4*)(carrier + rowbase + 4);
    a[0] = (a[0] + c0.x) * 0.5f; a[1] = (a[1] + c0.y) * 0.5f;
    a[2] = (a[2] + c0.z) * 0.5f; a[3] = (a[3] + c0.w) * 0.5f;
    a[4] = (a[4] + c1.x) * 0.5f; a[5] = (a[5] + c1.y) * 0.5f;
    a[6] = (a[6] + c1.z) * 0.5f; a[7] = (a[7] + c1.w) * 0.5f;
  }
  if(mode){
    *(float4*)(carrier + rowbase)     = make_float4(a[0], a[1], a[2], a[3]);
    *(float4*)(carrier + rowbase + 4) = make_float4(a[4], a[5], a[6], a[7]);
  }
  unsigned short hs[8], ls[8];
  #pragma unroll
  for(int j = 0; j < 8; ++j){
    unsigned short h = f2bf(a[j]);
    hs[j] = h;
    ls[j] = f2bf(a[j] - bf2f(h));
  }
  uint4 oh = make_uint4((unsigned)hs[0] | ((unsigned)hs[1] << 16),
                        (unsigned)hs[2] | ((unsigned)hs[3] << 16),
                        (unsigned)hs[4] | ((unsigned)hs[5] << 16),
                        (unsigned)hs[6] | ((unsigned)hs[7] << 16));
  uint4 ol = make_uint4((unsigned)ls[0] | ((unsigned)ls[1] << 16),
                        (unsigned)ls[2] | ((unsigned)ls[3] << 16),
                        (unsigned)ls[4] | ((unsigned)ls[5] << 16),
                        (unsigned)ls[6] | ((unsigned)ls[7] << 16));
  *(uint4*)(Hhi + rowbase) = oh;
  *(uint4*)(Hlo + rowbase) = ol;
}

// ---------------- output layer (Dout=3), f32 throughout ----------------
__global__ __launch_bounds__(256) void k_out_sup(const float* __restrict__ h,
    const float* __restrict__ Wo, float* __restrict__ sup3){
  const int gid = blockIdx.x * 4 + (threadIdx.x >> 6);
  const int lane = threadIdx.x & 63;
  if(gid >= MROWS) return;
  const float4 v = *(const float4*)(h + (size_t)gid * 256 + lane * 4);
  const float hv[4] = {v.x, v.y, v.z, v.w};
  float p0 = 0.f, p1 = 0.f, p2 = 0.f;
  #pragma unroll
  for(int j = 0; j < 4; ++j){
    const int k = lane * 4 + j;
    p0 = fmaf(hv[j], Wo[k * 3 + 0], p0);
    p1 = fmaf(hv[j], Wo[k * 3 + 1], p1);
    p2 = fmaf(hv[j], Wo[k * 3 + 2], p2);
  }
  #pragma unroll
  for(int off = 32; off; off >>= 1){
    p0 += __shfl_xor(p0, off, 64);
    p1 += __shfl_xor(p1, off, 64);
    p2 += __shfl_xor(p2, off, 64);
  }
  if(lane == 0){
    float* o = sup3 + (size_t)gid * 3;
    o[0] = p0; o[1] = p1; o[2] = p2;
  }
}

__global__ __launch_bounds__(256) void k_out_final(const float* __restrict__ h,
    const float* __restrict__ LWo, const float* __restrict__ bo,
    const int* __restrict__ rp, const int* __restrict__ ci, const float* __restrict__ vw,
    const float* __restrict__ sup3, float* __restrict__ out){
  const int gid = blockIdx.x * 4 + (threadIdx.x >> 6);
  const int lane = threadIdx.x & 63;
  if(gid >= MROWS) return;
  const int b = gid / NN, n = gid % NN;
  const float4 v = *(const float4*)(h + (size_t)gid * 256 + lane * 4);
  const float hv[4] = {v.x, v.y, v.z, v.w};
  float p0 = 0.f, p1 = 0.f, p2 = 0.f;
  #pragma unroll
  for(int j = 0; j < 4; ++j){
    const int k = lane * 4 + j;
    p0 = fmaf(hv[j], LWo[k * 3 + 0], p0);
    p1 = fmaf(hv[j], LWo[k * 3 + 1], p1);
    p2 = fmaf(hv[j], LWo[k * 3 + 2], p2);
  }
  const int s = rp[n], e = rp[n + 1];
  for(int i = s + lane; i < e; i += 64){
    const int src = ci[i];
    const float w = vw[i];
    const float* sp = sup3 + ((size_t)b * NN + src) * 3;
    p0 = fmaf(w, sp[0], p0);
    p1 = fmaf(w, sp[1], p1);
    p2 = fmaf(w, sp[2], p2);
  }
  #pragma unroll
  for(int off = 32; off; off >>= 1){
    p0 += __shfl_xor(p0, off, 64);
    p1 += __shfl_xor(p1, off, 64);
    p2 += __shfl_xor(p2, off, 64);
  }
  if(lane == 0){
    float* o = out + (size_t)gid * 3;
    o[0] = p0 + bo[0]; o[1] = p1 + bo[1]; o[2] = p2 + bo[2];
  }
}

// ---------------- host ----------------
extern "C" void kernel_launch(void* const* d_in, const int* in_sizes, int n_in,
                              void* d_out, int out_size, void* d_ws, size_t ws_size,
                              hipStream_t stream) {
  const float* x     = (const float*)d_in[0];
  const int*   esrc  = (const int*)d_in[1];
  const int*   edst  = (const int*)d_in[2];
  const float* ew    = (const float*)d_in[3];
  const float* W_in  = (const float*)d_in[4];
  const float* LW_in = (const float*)d_in[5];
  const float* b_in  = (const float*)d_in[6];
  const float* W_blk = (const float*)d_in[7];
  const float* LW_blk= (const float*)d_in[8];
  const float* b_blk = (const float*)d_in[9];
  const float* W_out = (const float*)d_in[10];
  const float* LW_out= (const float*)d_in[11];
  const float* b_out = (const float*)d_in[12];
  const int E = in_sizes[1];

  float* outF    = (float*)d_out;
  float* xout    = outF;                 // [B,N,3]
  float* carrier = outF + 240000;        // h region [B,N,256] f32; doubles as xhi scratch pre-layer0
  unsigned short* xhi = (unsigned short*)carrier;   // 40.96M bf16 = exactly the h region

  char* ws = (char*)d_ws;
  size_t off = 0;
  auto alloc = [&](size_t bytes) -> char* {
    char* p = ws + off;
    off += (bytes + 255) & ~(size_t)255;
    return p;
  };
  const size_t HB = (size_t)20480000 * 2;           // one bf16 activation buffer
  unsigned short* HaHi = (unsigned short*)alloc(HB);
  unsigned short* HaLo = (unsigned short*)alloc(HB);
  unsigned short* HbHi = (unsigned short*)alloc(2 * HB);  // pair contiguous; doubles as xlo
  unsigned short* HbLo = HbHi + 20480000;
  unsigned short* xlo  = HbHi;
  unsigned short* Sup  = (unsigned short*)alloc(HB);
  float*          Loc  = (float*)alloc((size_t)20480000 * 4);
  const int WTOT = 512 * 512 + 12 * 512 * 256;
  unsigned short* WtHi = (unsigned short*)alloc((size_t)WTOT * 2);
  unsigned short* WtLo = (unsigned short*)alloc((size_t)WTOT * 2);
  float* sup3    = (float*)alloc((size_t)240000 * 4);
  int*   counts  = (int*)alloc((size_t)2 * NN * 4);   // counts + cursor contiguous
  int*   cursor  = counts + NN;
  int*   rp      = (int*)alloc((size_t)(NN + 1) * 4);
  int*   ci      = (int*)alloc((size_t)E * 4);
  float* vw      = (float*)alloc((size_t)E * 4);
  (void)ws_size; (void)n_in; (void)out_size;

  // CSR build (deterministic: rows sorted by edge id)
  hipMemsetAsync(counts, 0, (size_t)2 * NN * 4, stream);
  k_count<<<(E + 255) / 256, 256, 0, stream>>>(edst, E, counts);
  k_scan<<<1, 1024, 0, stream>>>(counts, rp);
  k_fill<<<(E + 255) / 256, 256, 0, stream>>>(edst, E, rp, cursor, ci);
  k_sort_rows<<<(NN + 255) / 256, 256, 0, stream>>>(rp, ci, vw, esrc, ew);

  // split x -> bf16 hi/lo ; pack transposed weights hi/lo
  k_split<<<(10240000 + 255) / 256, 256, 0, stream>>>((const float4*)x, (ushort4*)xhi, (ushort4*)xlo, 10240000);
  k_pack_w<<<(WTOT + 255) / 256, 256, 0, stream>>>(W_in, LW_in, W_blk, LW_blk, WtHi, WtLo);

  dim3 gg(625, 4), gb(256);
  // layer 0 (K=512)
  k_gemm_dual<<<gg, gb, 0, stream>>>(xhi, xlo, WtHi, WtLo, Sup, Loc, 512);
  k_agg<<<NN, 256, 0, stream>>>(Sup, Loc, b_in, rp, ci, vw, HaHi, HaLo, carrier, 1);

  const unsigned short* WmHi = WtHi + 512 * 512;
  const unsigned short* WmLo = WtLo + 512 * 512;
  for(int l = 0; l < 6; ++l){
    const int li0 = 2 * l, li1 = 2 * l + 1;
    k_gemm_dual<<<gg, gb, 0, stream>>>(HaHi, HaLo, WmHi + (size_t)li0 * 131072, WmLo + (size_t)li0 * 131072, Sup, Loc, 256);
    k_agg<<<NN, 256, 0, stream>>>(Sup, Loc, b_blk + li0 * 256, rp, ci, vw, HbHi, HbLo, carrier, 0);
    k_gemm_dual<<<gg, gb, 0, stream>>>(HbHi, HbLo, WmHi + (size_t)li1 * 131072, WmLo + (size_t)li1 * 131072, Sup, Loc, 256);
    k_agg<<<NN, 256, 0, stream>>>(Sup, Loc, b_blk + li1 * 256, rp, ci, vw, HaHi, HaLo, carrier, 2);
  }

  // output layer, f32 from carrier
  k_out_sup<<<MROWS / 4, 256, 0, stream>>>(carrier, W_out, sup3);
  k_out_final<<<MROWS / 4, 256, 0, stream>>>(carrier, LW_out, b_out, rp, ci, vw, sup3, xout);
}

// Round 2
// 2834.337 us; speedup vs baseline: 1.0975x; 1.0975x over previous
//
#include <hip/hip_runtime.h>

#define NN 10000
#define BB 8
#define MROWS 80000   // BB*NN

typedef float f32x4 __attribute__((ext_vector_type(4)));
typedef __bf16 bf16x8 __attribute__((ext_vector_type(8)));

typedef __attribute__((address_space(1))) void as1_void;
typedef __attribute__((address_space(3))) void as3_void;

static __device__ __forceinline__ void gl_lds16(const void* g, void* l){
  __builtin_amdgcn_global_load_lds((as1_void*)g, (as3_void*)l, 16, 0, 0);
}

static __device__ __forceinline__ unsigned short f2bf(float f){
  unsigned u = __float_as_uint(f);
  u = u + 0x7fffu + ((u >> 16) & 1u);
  return (unsigned short)(u >> 16);
}
static __device__ __forceinline__ float bf2f(unsigned short h){
  return __uint_as_float(((unsigned)h) << 16);
}
static __device__ __forceinline__ float bflo(unsigned v){ return __uint_as_float(v << 16); }
static __device__ __forceinline__ float bfhi(unsigned v){ return __uint_as_float(v & 0xffff0000u); }

// ---------------- CSR build ----------------
__global__ void k_count(const int* __restrict__ dst, int E, int* __restrict__ counts){
  int i = blockIdx.x * blockDim.x + threadIdx.x;
  if(i < E) atomicAdd(&counts[dst[i]], 1);
}

__global__ void k_scan(const int* __restrict__ counts, int* __restrict__ rp){
  __shared__ int buf[1024];
  __shared__ int carry;
  const int t = threadIdx.x;
  if(t == 0){ carry = 0; rp[0] = 0; }
  __syncthreads();
  for(int base = 0; base < NN; base += 1024){
    int v = (base + t < NN) ? counts[base + t] : 0;
    buf[t] = v;
    __syncthreads();
    for(int off = 1; off < 1024; off <<= 1){
      int x = (t >= off) ? buf[t - off] : 0;
      __syncthreads();
      buf[t] += x;
      __syncthreads();
    }
    if(base + t < NN) rp[base + t + 1] = carry + buf[t];
    __syncthreads();
    if(t == 0) carry += buf[1023];
    __syncthreads();
  }
}

__global__ void k_fill(const int* __restrict__ dst, int E, const int* __restrict__ rp,
                       int* __restrict__ cursor, int* __restrict__ ci){
  int i = blockIdx.x * blockDim.x + threadIdx.x;
  if(i < E){
    int d = dst[i];
    int p = rp[d] + atomicAdd(&cursor[d], 1);
    ci[p] = i;   // edge id, sorted deterministically afterwards
  }
}

__global__ void k_sort_rows(const int* __restrict__ rp, int* __restrict__ ci, float* __restrict__ vw,
                            const int* __restrict__ esrc, const float* __restrict__ ew){
  const int n = blockIdx.x * blockDim.x + threadIdx.x;
  if(n >= NN) return;
  const int s = rp[n], e = rp[n + 1];
  for(int i = s; i < e - 1; ++i){           // selection sort by edge id (unique) -> deterministic
    int mj = i, mv = ci[i];
    for(int j = i + 1; j < e; ++j){
      int v = ci[j];
      if(v < mv){ mv = v; mj = j; }
    }
    ci[mj] = ci[i]; ci[i] = mv;
  }
  for(int p = s; p < e; ++p){
    int eid = ci[p];
    ci[p] = esrc[eid];
    vw[p] = ew[eid];
  }
}

// ---------------- f32 -> bf16 hi/lo split ----------------
__global__ void k_split(const float4* __restrict__ in, ushort4* __restrict__ hi,
                        ushort4* __restrict__ lo, int n4){
  int i = blockIdx.x * blockDim.x + threadIdx.x;
  if(i >= n4) return;
  float4 v = in[i];
  ushort4 h, l;
  h.x = f2bf(v.x); l.x = f2bf(v.x - bf2f(h.x));
  h.y = f2bf(v.y); l.y = f2bf(v.y - bf2f(h.y));
  h.z = f2bf(v.z); l.z = f2bf(v.z - bf2f(h.z));
  h.w = f2bf(v.w); l.w = f2bf(v.w - bf2f(h.w));
  hi[i] = h; lo[i] = l;
}

// Pack weights transposed: Wt[c][k] = W[k][c], hi/lo split.
// layout: [0, 512*512): layer0 (K=512, cols 0..255 = W_in, 256..511 = LW_in)
//         then 12 x [512][256] for W_blk/LW_blk
__global__ void k_pack_w(const float* __restrict__ Wi, const float* __restrict__ LWi,
                         const float* __restrict__ Wb, const float* __restrict__ LWb,
                         unsigned short* __restrict__ dh, unsigned short* __restrict__ dl){
  const int T0 = 512 * 512;
  const int TOT = T0 + 12 * 512 * 256;
  int i = blockIdx.x * blockDim.x + threadIdx.x;
  if(i >= TOT) return;
  float v;
  if(i < T0){
    int c = i >> 9, k = i & 511;
    v = (c < 256) ? Wi[k * 256 + c] : LWi[k * 256 + (c - 256)];
  } else {
    int j = i - T0;
    int li = j >> 17;          // 512*256 = 2^17
    int r = j & 131071;
    int c = r >> 8, k = r & 255;
    const float* src = (c < 256) ? (Wb + (size_t)li * 65536) : (LWb + (size_t)li * 65536);
    v = src[k * 256 + (c & 255)];
  }
  unsigned short h = f2bf(v);
  dh[i] = h;
  dl[i] = f2bf(v - bf2f(h));
}

// ---------------- dual GEMM: by=0 -> Sup (cols 0..255, bf16), by=1 -> Loc (cols 256..511, bf16)
// A: [80000, K] bf16 hi/lo,  Bt: [512, K] bf16 hi/lo (row = output col)
// BM=64, BN=256 : A fetched only 2x total (vs 4x with 128x128 tiles).
__global__ __launch_bounds__(256) void k_gemm_dual(
    const unsigned short* __restrict__ Ahi, const unsigned short* __restrict__ Alo,
    const unsigned short* __restrict__ Bhi, const unsigned short* __restrict__ Blo,
    unsigned short* __restrict__ Sup, unsigned short* __restrict__ Loc, int K)
{
  __shared__ unsigned short AsH[64 * 32];    // 4 KB
  __shared__ unsigned short AsL[64 * 32];    // 4 KB
  __shared__ unsigned short BsH[256 * 32];   // 16 KB
  __shared__ unsigned short BsL[256 * 32];   // 16 KB
  const int t = threadIdx.x;
  const int m0 = blockIdx.x << 6;
  const int by = blockIdx.y;              // 0 -> Sup, 1 -> Loc
  const int n0 = by << 8;
  const int lane = t & 63, wv = t >> 6;
  const int wn = wv << 6;                 // 4 waves tile N: 0,64,128,192
  const int rA = lane & 15, g = lane >> 4;
  f32x4 acc[4][4] = {};
  const int nsteps = K >> 5;
  const int rowt = t >> 2;                // 0..63
  const int cbt  = (t & 3) << 3;          // ushort offset within 32-k row: 0,8,16,24

  for(int s = 0; s < nsteps; ++s){
    const int k0 = s << 5;
    const size_t aoff = (size_t)(m0 + rowt) * K + k0 + cbt;
    gl_lds16(Ahi + aoff, (char*)AsH + t * 16);
    gl_lds16(Alo + aoff, (char*)AsL + t * 16);
    #pragma unroll
    for(int q = 0; q < 4; ++q){
      const size_t boff = (size_t)(n0 + q * 64 + rowt) * K + k0 + cbt;
      gl_lds16(Bhi + boff, (char*)BsH + q * 4096 + t * 16);
      gl_lds16(Blo + boff, (char*)BsL + q * 4096 + t * 16);
    }
    __syncthreads();
    bf16x8 ah[4], al[4], bh[4], bl[4];
    #pragma unroll
    for(int mi = 0; mi < 4; ++mi){
      const int ao = (mi * 16 + rA) * 32 + g * 8;
      ah[mi] = *(const bf16x8*)(AsH + ao);
      al[mi] = *(const bf16x8*)(AsL + ao);
    }
    #pragma unroll
    for(int ni = 0; ni < 4; ++ni){
      const int bo = (wn + ni * 16 + rA) * 32 + g * 8;
      bh[ni] = *(const bf16x8*)(BsH + bo);
      bl[ni] = *(const bf16x8*)(BsL + bo);
    }
    #pragma unroll
    for(int mi = 0; mi < 4; ++mi){
      #pragma unroll
      for(int ni = 0; ni < 4; ++ni){
        f32x4 c = acc[mi][ni];
        c = __builtin_amdgcn_mfma_f32_16x16x32_bf16(al[mi], bh[ni], c, 0, 0, 0);
        c = __builtin_amdgcn_mfma_f32_16x16x32_bf16(ah[mi], bl[ni], c, 0, 0, 0);
        c = __builtin_amdgcn_mfma_f32_16x16x32_bf16(ah[mi], bh[ni], c, 0, 0, 0);
        acc[mi][ni] = c;
      }
    }
    __syncthreads();
  }

  unsigned short* dst = (by == 0) ? Sup : Loc;
  #pragma unroll
  for(int mi = 0; mi < 4; ++mi){
    const int rowb = m0 + mi * 16 + g * 4;
    #pragma unroll
    for(int ni = 0; ni < 4; ++ni){
      const int col = wn + ni * 16 + rA;
      #pragma unroll
      for(int r = 0; r < 4; ++r){
        dst[(size_t)(rowb + r) * 256 + col] = f2bf(acc[mi][ni][r]);
      }
    }
  }
}

// ---------------- aggregation + local + bias (+residual), hi/lo split output ----------------
// mode 0: Hnext only
// mode 1: carrier = t; Hnext
// mode 2: carrier = (carrier + t)*0.5; Hnext
// mode 3: carrier = (carrier + t)*0.5; NO Hnext (last layer)
__global__ __launch_bounds__(256) void k_agg(
    const unsigned short* __restrict__ Sup, const unsigned short* __restrict__ Loc,
    const float* __restrict__ bias,
    const int* __restrict__ rp, const int* __restrict__ ci, const float* __restrict__ vw,
    unsigned short* __restrict__ Hhi, unsigned short* __restrict__ Hlo,
    float* __restrict__ carrier, const int mode)
{
  const int n = blockIdx.x;
  const int t = threadIdx.x;
  const int b = t >> 5;
  const int d0 = (t & 31) << 3;
  const size_t rowbase = ((size_t)b * NN + n) * 256 + d0;
  float a[8];
  {
    const uint4 lv = *(const uint4*)(Loc + rowbase);   // 8 bf16 local values
    float4 q0 = *(const float4*)(bias + d0);
    float4 q1 = *(const float4*)(bias + d0 + 4);
    a[0] = bflo(lv.x) + q0.x; a[1] = bfhi(lv.x) + q0.y;
    a[2] = bflo(lv.y) + q0.z; a[3] = bfhi(lv.y) + q0.w;
    a[4] = bflo(lv.z) + q1.x; a[5] = bfhi(lv.z) + q1.y;
    a[6] = bflo(lv.w) + q1.z; a[7] = bfhi(lv.w) + q1.w;
  }
  const int s = rp[n], e = rp[n + 1];
  const size_t bb = (size_t)b * NN * 256 + d0;
  for(int i = s; i < e; ++i){
    const int src = ci[i];
    const float w = vw[i];
    const uint4 sv = *(const uint4*)(Sup + bb + (size_t)src * 256);
    a[0] = fmaf(w, bflo(sv.x), a[0]);
    a[1] = fmaf(w, bfhi(sv.x), a[1]);
    a[2] = fmaf(w, bflo(sv.y), a[2]);
    a[3] = fmaf(w, bfhi(sv.y), a[3]);
    a[4] = fmaf(w, bflo(sv.z), a[4]);
    a[5] = fmaf(w, bfhi(sv.z), a[5]);
    a[6] = fmaf(w, bflo(sv.w), a[6]);
    a[7] = fmaf(w, bfhi(sv.w), a[7]);
  }
  if(mode >= 2){
    float4 c0 = *(const float4*)(carrier + rowbase);
    float4 c1 = *(const float4*)(carrier + rowbase + 4);
    a[0] = (a[0] + c0.x) * 0.5f; a[1] = (a[1] + c0.y) * 0.5f;
    a[2] = (a[2] + c0.z) * 0.5f; a[3] = (a[3] + c0.w) * 0.5f;
    a[4] = (a[4] + c1.x) * 0.5f; a[5] = (a[5] + c1.y) * 0.5f;
    a[6] = (a[6] + c1.z) * 0.5f; a[7] = (a[7] + c1.w) * 0.5f;
  }
  if(mode){
    *(float4*)(carrier + rowbase)     = make_float4(a[0], a[1], a[2], a[3]);
    *(float4*)(carrier + rowbase + 4) = make_float4(a[4], a[5], a[6], a[7]);
  }
  if(mode == 3) return;
  unsigned short hs[8], ls[8];
  #pragma unroll
  for(int j = 0; j < 8; ++j){
    unsigned short h = f2bf(a[j]);
    hs[j] = h;
    ls[j] = f2bf(a[j] - bf2f(h));
  }
  uint4 oh = make_uint4((unsigned)hs[0] | ((unsigned)hs[1] << 16),
                        (unsigned)hs[2] | ((unsigned)hs[3] << 16),
                        (unsigned)hs[4] | ((unsigned)hs[5] << 16),
                        (unsigned)hs[6] | ((unsigned)hs[7] << 16));
  uint4 ol = make_uint4((unsigned)ls[0] | ((unsigned)ls[1] << 16),
                        (unsigned)ls[2] | ((unsigned)ls[3] << 16),
                        (unsigned)ls[4] | ((unsigned)ls[5] << 16),
                        (unsigned)ls[6] | ((unsigned)ls[7] << 16));
  *(uint4*)(Hhi + rowbase) = oh;
  *(uint4*)(Hlo + rowbase) = ol;
}

// ---------------- output layer (Dout=3), f32 throughout ----------------
__global__ __launch_bounds__(256) void k_out_sup(const float* __restrict__ h,
    const float* __restrict__ Wo, float* __restrict__ sup3){
  const int gid = blockIdx.x * 4 + (threadIdx.x >> 6);
  const int lane = threadIdx.x & 63;
  if(gid >= MROWS) return;
  const float4 v = *(const float4*)(h + (size_t)gid * 256 + lane * 4);
  const float hv[4] = {v.x, v.y, v.z, v.w};
  float p0 = 0.f, p1 = 0.f, p2 = 0.f;
  #pragma unroll
  for(int j = 0; j < 4; ++j){
    const int k = lane * 4 + j;
    p0 = fmaf(hv[j], Wo[k * 3 + 0], p0);
    p1 = fmaf(hv[j], Wo[k * 3 + 1], p1);
    p2 = fmaf(hv[j], Wo[k * 3 + 2], p2);
  }
  #pragma unroll
  for(int off = 32; off; off >>= 1){
    p0 += __shfl_xor(p0, off, 64);
    p1 += __shfl_xor(p1, off, 64);
    p2 += __shfl_xor(p2, off, 64);
  }
  if(lane == 0){
    float* o = sup3 + (size_t)gid * 3;
    o[0] = p0; o[1] = p1; o[2] = p2;
  }
}

__global__ __launch_bounds__(256) void k_out_final(const float* __restrict__ h,
    const float* __restrict__ LWo, const float* __restrict__ bo,
    const int* __restrict__ rp, const int* __restrict__ ci, const float* __restrict__ vw,
    const float* __restrict__ sup3, float* __restrict__ out){
  const int gid = blockIdx.x * 4 + (threadIdx.x >> 6);
  const int lane = threadIdx.x & 63;
  if(gid >= MROWS) return;
  const int b = gid / NN, n = gid % NN;
  const float4 v = *(const float4*)(h + (size_t)gid * 256 + lane * 4);
  const float hv[4] = {v.x, v.y, v.z, v.w};
  float p0 = 0.f, p1 = 0.f, p2 = 0.f;
  #pragma unroll
  for(int j = 0; j < 4; ++j){
    const int k = lane * 4 + j;
    p0 = fmaf(hv[j], LWo[k * 3 + 0], p0);
    p1 = fmaf(hv[j], LWo[k * 3 + 1], p1);
    p2 = fmaf(hv[j], LWo[k * 3 + 2], p2);
  }
  const int s = rp[n], e = rp[n + 1];
  for(int i = s + lane; i < e; i += 64){
    const int src = ci[i];
    const float w = vw[i];
    const float* sp = sup3 + ((size_t)b * NN + src) * 3;
    p0 = fmaf(w, sp[0], p0);
    p1 = fmaf(w, sp[1], p1);
    p2 = fmaf(w, sp[2], p2);
  }
  #pragma unroll
  for(int off = 32; off; off >>= 1){
    p0 += __shfl_xor(p0, off, 64);
    p1 += __shfl_xor(p1, off, 64);
    p2 += __shfl_xor(p2, off, 64);
  }
  if(lane == 0){
    float* o = out + (size_t)gid * 3;
    o[0] = p0 + bo[0]; o[1] = p1 + bo[1]; o[2] = p2 + bo[2];
  }
}

// ---------------- host ----------------
extern "C" void kernel_launch(void* const* d_in, const int* in_sizes, int n_in,
                              void* d_out, int out_size, void* d_ws, size_t ws_size,
                              hipStream_t stream) {
  const float* x     = (const float*)d_in[0];
  const int*   esrc  = (const int*)d_in[1];
  const int*   edst  = (const int*)d_in[2];
  const float* ew    = (const float*)d_in[3];
  const float* W_in  = (const float*)d_in[4];
  const float* LW_in = (const float*)d_in[5];
  const float* b_in  = (const float*)d_in[6];
  const float* W_blk = (const float*)d_in[7];
  const float* LW_blk= (const float*)d_in[8];
  const float* b_blk = (const float*)d_in[9];
  const float* W_out = (const float*)d_in[10];
  const float* LW_out= (const float*)d_in[11];
  const float* b_out = (const float*)d_in[12];
  const int E = in_sizes[1];

  float* outF    = (float*)d_out;
  float* xout    = outF;                 // [B,N,3]
  float* carrier = outF + 240000;        // h region [B,N,256] f32; doubles as xhi scratch pre-layer0
  unsigned short* xhi = (unsigned short*)carrier;   // 40.96M bf16 = exactly the h region

  char* ws = (char*)d_ws;
  size_t off = 0;
  auto alloc = [&](size_t bytes) -> char* {
    char* p = ws + off;
    off += (bytes + 255) & ~(size_t)255;
    return p;
  };
  const size_t HB = (size_t)20480000 * 2;           // one bf16 activation buffer
  unsigned short* HaHi = (unsigned short*)alloc(HB);
  unsigned short* HaLo = (unsigned short*)alloc(HB);
  unsigned short* HbHi = (unsigned short*)alloc(2 * HB);  // pair contiguous; doubles as xlo
  unsigned short* HbLo = HbHi + 20480000;
  unsigned short* xlo  = HbHi;
  unsigned short* Sup  = (unsigned short*)alloc(HB);
  unsigned short* Loc  = (unsigned short*)alloc(HB);
  const int WTOT = 512 * 512 + 12 * 512 * 256;
  unsigned short* WtHi = (unsigned short*)alloc((size_t)WTOT * 2);
  unsigned short* WtLo = (unsigned short*)alloc((size_t)WTOT * 2);
  float* sup3    = (float*)alloc((size_t)240000 * 4);
  int*   counts  = (int*)alloc((size_t)2 * NN * 4);   // counts + cursor contiguous
  int*   cursor  = counts + NN;
  int*   rp      = (int*)alloc((size_t)(NN + 1) * 4);
  int*   ci      = (int*)alloc((size_t)E * 4);
  float* vw      = (float*)alloc((size_t)E * 4);
  (void)ws_size; (void)n_in; (void)out_size;

  // CSR build (deterministic: rows sorted by edge id)
  hipMemsetAsync(counts, 0, (size_t)2 * NN * 4, stream);
  k_count<<<(E + 255) / 256, 256, 0, stream>>>(edst, E, counts);
  k_scan<<<1, 1024, 0, stream>>>(counts, rp);
  k_fill<<<(E + 255) / 256, 256, 0, stream>>>(edst, E, rp, cursor, ci);
  k_sort_rows<<<(NN + 255) / 256, 256, 0, stream>>>(rp, ci, vw, esrc, ew);

  // split x -> bf16 hi/lo ; pack transposed weights hi/lo
  k_split<<<(10240000 + 255) / 256, 256, 0, stream>>>((const float4*)x, (ushort4*)xhi, (ushort4*)xlo, 10240000);
  k_pack_w<<<(WTOT + 255) / 256, 256, 0, stream>>>(W_in, LW_in, W_blk, LW_blk, WtHi, WtLo);

  dim3 gg(1250, 2), gb(256);
  // layer 0 (K=512)
  k_gemm_dual<<<gg, gb, 0, stream>>>(xhi, xlo, WtHi, WtLo, Sup, Loc, 512);
  k_agg<<<NN, 256, 0, stream>>>(Sup, Loc, b_in, rp, ci, vw, HaHi, HaLo, carrier, 1);

  const unsigned short* WmHi = WtHi + 512 * 512;
  const unsigned short* WmLo = WtLo + 512 * 512;
  for(int l = 0; l < 6; ++l){
    const int li0 = 2 * l, li1 = 2 * l + 1;
    k_gemm_dual<<<gg, gb, 0, stream>>>(HaHi, HaLo, WmHi + (size_t)li0 * 131072, WmLo + (size_t)li0 * 131072, Sup, Loc, 256);
    k_agg<<<NN, 256, 0, stream>>>(Sup, Loc, b_blk + li0 * 256, rp, ci, vw, HbHi, HbLo, carrier, 0);
    k_gemm_dual<<<gg, gb, 0, stream>>>(HbHi, HbLo, WmHi + (size_t)li1 * 131072, WmLo + (size_t)li1 * 131072, Sup, Loc, 256);
    k_agg<<<NN, 256, 0, stream>>>(Sup, Loc, b_blk + li1 * 256, rp, ci, vw, HaHi, HaLo, carrier, (l == 5) ? 3 : 2);
  }

  // output layer, f32 from carrier
  k_out_sup<<<MROWS / 4, 256, 0, stream>>>(carrier, W_out, sup3);
  k_out_final<<<MROWS / 4, 256, 0, stream>>>(carrier, LW_out, b_out, rp, ci, vw, sup3, xout);
}

// Round 3
// 2783.235 us; speedup vs baseline: 1.1177x; 1.0184x over previous
//
#include <hip/hip_runtime.h>

#define NN 10000
#define BB 8
#define MROWS 80000   // BB*NN

typedef float f32x4 __attribute__((ext_vector_type(4)));
typedef __bf16 bf16x8 __attribute__((ext_vector_type(8)));

typedef __attribute__((address_space(1))) void as1_void;
typedef __attribute__((address_space(3))) void as3_void;

static __device__ __forceinline__ void gl_lds16(const void* g, void* l){
  __builtin_amdgcn_global_load_lds((as1_void*)g, (as3_void*)l, 16, 0, 0);
}

static __device__ __forceinline__ unsigned short f2bf(float f){
  unsigned u = __float_as_uint(f);
  u = u + 0x7fffu + ((u >> 16) & 1u);
  return (unsigned short)(u >> 16);
}
static __device__ __forceinline__ float bf2f(unsigned short h){
  return __uint_as_float(((unsigned)h) << 16);
}
static __device__ __forceinline__ float bflo(unsigned v){ return __uint_as_float(v << 16); }
static __device__ __forceinline__ float bfhi(unsigned v){ return __uint_as_float(v & 0xffff0000u); }

// ---------------- CSR build ----------------
__global__ void k_count(const int* __restrict__ dst, int E, int* __restrict__ counts){
  int i = blockIdx.x * blockDim.x + threadIdx.x;
  if(i < E) atomicAdd(&counts[dst[i]], 1);
}

__global__ void k_scan(const int* __restrict__ counts, int* __restrict__ rp){
  __shared__ int buf[1024];
  __shared__ int carry;
  const int t = threadIdx.x;
  if(t == 0){ carry = 0; rp[0] = 0; }
  __syncthreads();
  for(int base = 0; base < NN; base += 1024){
    int v = (base + t < NN) ? counts[base + t] : 0;
    buf[t] = v;
    __syncthreads();
    for(int off = 1; off < 1024; off <<= 1){
      int x = (t >= off) ? buf[t - off] : 0;
      __syncthreads();
      buf[t] += x;
      __syncthreads();
    }
    if(base + t < NN) rp[base + t + 1] = carry + buf[t];
    __syncthreads();
    if(t == 0) carry += buf[1023];
    __syncthreads();
  }
}

__global__ void k_fill(const int* __restrict__ dst, int E, const int* __restrict__ rp,
                       int* __restrict__ cursor, int* __restrict__ ci){
  int i = blockIdx.x * blockDim.x + threadIdx.x;
  if(i < E){
    int d = dst[i];
    int p = rp[d] + atomicAdd(&cursor[d], 1);
    ci[p] = i;   // edge id, sorted deterministically afterwards
  }
}

__global__ void k_sort_rows(const int* __restrict__ rp, int* __restrict__ ci, float* __restrict__ vw,
                            const int* __restrict__ esrc, const float* __restrict__ ew){
  const int n = blockIdx.x * blockDim.x + threadIdx.x;
  if(n >= NN) return;
  const int s = rp[n], e = rp[n + 1];
  for(int i = s; i < e - 1; ++i){           // selection sort by edge id (unique) -> deterministic
    int mj = i, mv = ci[i];
    for(int j = i + 1; j < e; ++j){
      int v = ci[j];
      if(v < mv){ mv = v; mj = j; }
    }
    ci[mj] = ci[i]; ci[i] = mv;
  }
  for(int p = s; p < e; ++p){
    int eid = ci[p];
    ci[p] = esrc[eid];
    vw[p] = ew[eid];
  }
}

// ---------------- f32 -> bf16 hi/lo split ----------------
__global__ void k_split(const float4* __restrict__ in, ushort4* __restrict__ hi,
                        ushort4* __restrict__ lo, int n4){
  int i = blockIdx.x * blockDim.x + threadIdx.x;
  if(i >= n4) return;
  float4 v = in[i];
  ushort4 h, l;
  h.x = f2bf(v.x); l.x = f2bf(v.x - bf2f(h.x));
  h.y = f2bf(v.y); l.y = f2bf(v.y - bf2f(h.y));
  h.z = f2bf(v.z); l.z = f2bf(v.z - bf2f(h.z));
  h.w = f2bf(v.w); l.w = f2bf(v.w - bf2f(h.w));
  hi[i] = h; lo[i] = l;
}

// Pack weights transposed: Wt[c][k] = W[k][c], hi/lo split.
__global__ void k_pack_w(const float* __restrict__ Wi, const float* __restrict__ LWi,
                         const float* __restrict__ Wb, const float* __restrict__ LWb,
                         unsigned short* __restrict__ dh, unsigned short* __restrict__ dl){
  const int T0 = 512 * 512;
  const int TOT = T0 + 12 * 512 * 256;
  int i = blockIdx.x * blockDim.x + threadIdx.x;
  if(i >= TOT) return;
  float v;
  if(i < T0){
    int c = i >> 9, k = i & 511;
    v = (c < 256) ? Wi[k * 256 + c] : LWi[k * 256 + (c - 256)];
  } else {
    int j = i - T0;
    int li = j >> 17;          // 512*256 = 2^17
    int r = j & 131071;
    int c = r >> 8, k = r & 255;
    const float* src = (c < 256) ? (Wb + (size_t)li * 65536) : (LWb + (size_t)li * 65536);
    v = src[k * 256 + (c & 255)];
  }
  unsigned short h = f2bf(v);
  dh[i] = h;
  dl[i] = f2bf(v - bf2f(h));
}

// ---------------- dual GEMM: by=0 -> Sup, by=1 -> Loc (both bf16 out)
// A: [80000, K] bf16 hi/lo,  Bt: [512, K] bf16 hi/lo (row = output col)
// BM=64, BN=256. 2-phase pipeline (T3/T4): LDS double-buffered (80KB),
// STAGE(s+1) issued before compute(s), counted vmcnt(10) so next-tile HBM
// loads stay in flight across the compute phase.
// Bank-conflict fix (T2, both-sides per rule #21): global source chunk is
// pre-swizzled with chunk^=(row>>1)&3, LDS dest linear, read applies same XOR.
__global__ __launch_bounds__(256) void k_gemm_dual(
    const unsigned short* __restrict__ Ahi, const unsigned short* __restrict__ Alo,
    const unsigned short* __restrict__ Bhi, const unsigned short* __restrict__ Blo,
    unsigned short* __restrict__ Sup, unsigned short* __restrict__ Loc, int K)
{
  __shared__ unsigned short AsH[2][2048];   // 2 x 4 KB  (64 rows x 32 k)
  __shared__ unsigned short AsL[2][2048];
  __shared__ unsigned short BsH[2][8192];   // 2 x 16 KB (256 rows x 32 k)
  __shared__ unsigned short BsL[2][8192];
  const int t = threadIdx.x;
  const int m0 = blockIdx.x << 6;
  const int by = blockIdx.y;              // 0 -> Sup, 1 -> Loc
  const int n0 = by << 8;
  const int lane = t & 63, wv = t >> 6;
  const int rA = lane & 15, g = lane >> 4;
  f32x4 acc[4][4] = {};
  const int nsteps = K >> 5;
  const int rowt = t >> 2;                         // 0..63
  const int csw  = (t & 3) ^ ((rowt >> 1) & 3);    // pre-swizzled source chunk
  const int cbt  = csw << 3;                       // ushort offset 0/8/16/24

  // ---- staging: 10 x gl_lds16 per thread per K-step ----
  auto STAGE = [&](int s, int buf){
    const int k0 = s << 5;
    const size_t aoff = (size_t)(m0 + rowt) * K + k0 + cbt;
    gl_lds16(Ahi + aoff, (char*)AsH[buf] + t * 16);
    gl_lds16(Alo + aoff, (char*)AsL[buf] + t * 16);
    #pragma unroll
    for(int q = 0; q < 4; ++q){
      const size_t boff = (size_t)(n0 + q * 64 + rowt) * K + k0 + cbt;
      gl_lds16(Bhi + boff, (char*)BsH[buf] + q * 4096 + t * 16);
      gl_lds16(Blo + boff, (char*)BsL[buf] + q * 4096 + t * 16);
    }
  };

  STAGE(0, 0);
  int cur = 0;
  const int slotx = (rA >> 1) & 3;        // read-side XOR base

  for(int s = 0; s < nsteps; ++s){
    __builtin_amdgcn_sched_barrier(0);
    if(s + 1 < nsteps){
      STAGE(s + 1, cur ^ 1);
      asm volatile("s_waitcnt vmcnt(10)" ::: "memory");  // cur's 10 done, next 10 in flight
    } else {
      asm volatile("s_waitcnt vmcnt(0)" ::: "memory");
    }
    __builtin_amdgcn_s_barrier();
    __builtin_amdgcn_sched_barrier(0);

    bf16x8 ah[4], al[4], bh[4], bl[4];
    #pragma unroll
    for(int mi = 0; mi < 4; ++mi){
      const int ao = (mi * 16 + rA) * 32 + ((g ^ slotx) << 3);
      ah[mi] = *(const bf16x8*)(AsH[cur] + ao);
      al[mi] = *(const bf16x8*)(AsL[cur] + ao);
    }
    #pragma unroll
    for(int ni = 0; ni < 4; ++ni){
      const int bo = wv * 2048 + (ni * 16 + rA) * 32 + ((g ^ slotx) << 3);
      bh[ni] = *(const bf16x8*)(BsH[cur] + bo);
      bl[ni] = *(const bf16x8*)(BsL[cur] + bo);
    }
    #pragma unroll
    for(int mi = 0; mi < 4; ++mi){
      #pragma unroll
      for(int ni = 0; ni < 4; ++ni){
        f32x4 c = acc[mi][ni];
        c = __builtin_amdgcn_mfma_f32_16x16x32_bf16(al[mi], bh[ni], c, 0, 0, 0);
        c = __builtin_amdgcn_mfma_f32_16x16x32_bf16(ah[mi], bl[ni], c, 0, 0, 0);
        c = __builtin_amdgcn_mfma_f32_16x16x32_bf16(ah[mi], bh[ni], c, 0, 0, 0);
        acc[mi][ni] = c;
      }
    }
    __builtin_amdgcn_sched_barrier(0);
    __builtin_amdgcn_s_barrier();     // all waves done reading cur before it is restaged
    cur ^= 1;
  }

  unsigned short* dst = (by == 0) ? Sup : Loc;
  const int wn = wv << 6;
  #pragma unroll
  for(int mi = 0; mi < 4; ++mi){
    const int rowb = m0 + mi * 16 + g * 4;
    #pragma unroll
    for(int ni = 0; ni < 4; ++ni){
      const int col = wn + ni * 16 + rA;
      #pragma unroll
      for(int r = 0; r < 4; ++r){
        dst[(size_t)(rowb + r) * 256 + col] = f2bf(acc[mi][ni][r]);
      }
    }
  }
}

// ---------------- aggregation + local + bias (+residual), hi/lo split output ----------------
// mode 0: Hnext only
// mode 1: carrier = t; Hnext
// mode 2: carrier = (carrier + t)*0.5; Hnext
// mode 3: carrier = (carrier + t)*0.5; NO Hnext (last layer)
__global__ __launch_bounds__(256) void k_agg(
    const unsigned short* __restrict__ Sup, const unsigned short* __restrict__ Loc,
    const float* __restrict__ bias,
    const int* __restrict__ rp, const int* __restrict__ ci, const float* __restrict__ vw,
    unsigned short* __restrict__ Hhi, unsigned short* __restrict__ Hlo,
    float* __restrict__ carrier, const int mode)
{
  const int n = blockIdx.x;
  const int t = threadIdx.x;
  const int b = t >> 5;
  const int d0 = (t & 31) << 3;
  const size_t rowbase = ((size_t)b * NN + n) * 256 + d0;
  float a[8];
  {
    const uint4 lv = *(const uint4*)(Loc + rowbase);   // 8 bf16 local values
    float4 q0 = *(const float4*)(bias + d0);
    float4 q1 = *(const float4*)(bias + d0 + 4);
    a[0] = bflo(lv.x) + q0.x; a[1] = bfhi(lv.x) + q0.y;
    a[2] = bflo(lv.y) + q0.z; a[3] = bfhi(lv.y) + q0.w;
    a[4] = bflo(lv.z) + q1.x; a[5] = bfhi(lv.z) + q1.y;
    a[6] = bflo(lv.w) + q1.z; a[7] = bfhi(lv.w) + q1.w;
  }
  const int s = rp[n], e = rp[n + 1];
  const size_t bb = (size_t)b * NN * 256 + d0;
  for(int i = s; i < e; ++i){
    const int src = ci[i];
    const float w = vw[i];
    const uint4 sv = *(const uint4*)(Sup + bb + (size_t)src * 256);
    a[0] = fmaf(w, bflo(sv.x), a[0]);
    a[1] = fmaf(w, bfhi(sv.x), a[1]);
    a[2] = fmaf(w, bflo(sv.y), a[2]);
    a[3] = fmaf(w, bfhi(sv.y), a[3]);
    a[4] = fmaf(w, bflo(sv.z), a[4]);
    a[5] = fmaf(w, bfhi(sv.z), a[5]);
    a[6] = fmaf(w, bflo(sv.w), a[6]);
    a[7] = fmaf(w, bfhi(sv.w), a[7]);
  }
  if(mode >= 2){
    float4 c0 = *(const float4*)(carrier + rowbase);
    float4 c1 = *(const float4*)(carrier + rowbase + 4);
    a[0] = (a[0] + c0.x) * 0.5f; a[1] = (a[1] + c0.y) * 0.5f;
    a[2] = (a[2] + c0.z) * 0.5f; a[3] = (a[3] + c0.w) * 0.5f;
    a[4] = (a[4] + c1.x) * 0.5f; a[5] = (a[5] + c1.y) * 0.5f;
    a[6] = (a[6] + c1.z) * 0.5f; a[7] = (a[7] + c1.w) * 0.5f;
  }
  if(mode){
    *(float4*)(carrier + rowbase)     = make_float4(a[0], a[1], a[2], a[3]);
    *(float4*)(carrier + rowbase + 4) = make_float4(a[4], a[5], a[6], a[7]);
  }
  if(mode == 3) return;
  unsigned short hs[8], ls[8];
  #pragma unroll
  for(int j = 0; j < 8; ++j){
    unsigned short h = f2bf(a[j]);
    hs[j] = h;
    ls[j] = f2bf(a[j] - bf2f(h));
  }
  uint4 oh = make_uint4((unsigned)hs[0] | ((unsigned)hs[1] << 16),
                        (unsigned)hs[2] | ((unsigned)hs[3] << 16),
                        (unsigned)hs[4] | ((unsigned)hs[5] << 16),
                        (unsigned)hs[6] | ((unsigned)hs[7] << 16));
  uint4 ol = make_uint4((unsigned)ls[0] | ((unsigned)ls[1] << 16),
                        (unsigned)ls[2] | ((unsigned)ls[3] << 16),
                        (unsigned)ls[4] | ((unsigned)ls[5] << 16),
                        (unsigned)ls[6] | ((unsigned)ls[7] << 16));
  *(uint4*)(Hhi + rowbase) = oh;
  *(uint4*)(Hlo + rowbase) = ol;
}

// ---------------- output layer (Dout=3), f32 throughout ----------------
__global__ __launch_bounds__(256) void k_out_sup(const float* __restrict__ h,
    const float* __restrict__ Wo, float* __restrict__ sup3){
  const int gid = blockIdx.x * 4 + (threadIdx.x >> 6);
  const int lane = threadIdx.x & 63;
  if(gid >= MROWS) return;
  const float4 v = *(const float4*)(h + (size_t)gid * 256 + lane * 4);
  const float hv[4] = {v.x, v.y, v.z, v.w};
  float p0 = 0.f, p1 = 0.f, p2 = 0.f;
  #pragma unroll
  for(int j = 0; j < 4; ++j){
    const int k = lane * 4 + j;
    p0 = fmaf(hv[j], Wo[k * 3 + 0], p0);
    p1 = fmaf(hv[j], Wo[k * 3 + 1], p1);
    p2 = fmaf(hv[j], Wo[k * 3 + 2], p2);
  }
  #pragma unroll
  for(int off = 32; off; off >>= 1){
    p0 += __shfl_xor(p0, off, 64);
    p1 += __shfl_xor(p1, off, 64);
    p2 += __shfl_xor(p2, off, 64);
  }
  if(lane == 0){
    float* o = sup3 + (size_t)gid * 3;
    o[0] = p0; o[1] = p1; o[2] = p2;
  }
}

__global__ __launch_bounds__(256) void k_out_final(const float* __restrict__ h,
    const float* __restrict__ LWo, const float* __restrict__ bo,
    const int* __restrict__ rp, const int* __restrict__ ci, const float* __restrict__ vw,
    const float* __restrict__ sup3, float* __restrict__ out){
  const int gid = blockIdx.x * 4 + (threadIdx.x >> 6);
  const int lane = threadIdx.x & 63;
  if(gid >= MROWS) return;
  const int b = gid / NN, n = gid % NN;
  const float4 v = *(const float4*)(h + (size_t)gid * 256 + lane * 4);
  const float hv[4] = {v.x, v.y, v.z, v.w};
  float p0 = 0.f, p1 = 0.f, p2 = 0.f;
  #pragma unroll
  for(int j = 0; j < 4; ++j){
    const int k = lane * 4 + j;
    p0 = fmaf(hv[j], LWo[k * 3 + 0], p0);
    p1 = fmaf(hv[j], LWo[k * 3 + 1], p1);
    p2 = fmaf(hv[j], LWo[k * 3 + 2], p2);
  }
  const int s = rp[n], e = rp[n + 1];
  for(int i = s + lane; i < e; i += 64){
    const int src = ci[i];
    const float w = vw[i];
    const float* sp = sup3 + ((size_t)b * NN + src) * 3;
    p0 = fmaf(w, sp[0], p0);
    p1 = fmaf(w, sp[1], p1);
    p2 = fmaf(w, sp[2], p2);
  }
  #pragma unroll
  for(int off = 32; off; off >>= 1){
    p0 += __shfl_xor(p0, off, 64);
    p1 += __shfl_xor(p1, off, 64);
    p2 += __shfl_xor(p2, off, 64);
  }
  if(lane == 0){
    float* o = out + (size_t)gid * 3;
    o[0] = p0 + bo[0]; o[1] = p1 + bo[1]; o[2] = p2 + bo[2];
  }
}

// ---------------- host ----------------
extern "C" void kernel_launch(void* const* d_in, const int* in_sizes, int n_in,
                              void* d_out, int out_size, void* d_ws, size_t ws_size,
                              hipStream_t stream) {
  const float* x     = (const float*)d_in[0];
  const int*   esrc  = (const int*)d_in[1];
  const int*   edst  = (const int*)d_in[2];
  const float* ew    = (const float*)d_in[3];
  const float* W_in  = (const float*)d_in[4];
  const float* LW_in = (const float*)d_in[5];
  const float* b_in  = (const float*)d_in[6];
  const float* W_blk = (const float*)d_in[7];
  const float* LW_blk= (const float*)d_in[8];
  const float* b_blk = (const float*)d_in[9];
  const float* W_out = (const float*)d_in[10];
  const float* LW_out= (const float*)d_in[11];
  const float* b_out = (const float*)d_in[12];
  const int E = in_sizes[1];

  float* outF    = (float*)d_out;
  float* xout    = outF;                 // [B,N,3]
  float* carrier = outF + 240000;        // h region [B,N,256] f32; doubles as xhi scratch pre-layer0
  unsigned short* xhi = (unsigned short*)carrier;   // 40.96M bf16 = exactly the h region

  char* ws = (char*)d_ws;
  size_t off = 0;
  auto alloc = [&](size_t bytes) -> char* {
    char* p = ws + off;
    off += (bytes + 255) & ~(size_t)255;
    return p;
  };
  const size_t HB = (size_t)20480000 * 2;           // one bf16 activation buffer
  unsigned short* HaHi = (unsigned short*)alloc(HB);
  unsigned short* HaLo = (unsigned short*)alloc(HB);
  unsigned short* HbHi = (unsigned short*)alloc(2 * HB);  // pair contiguous; doubles as xlo
  unsigned short* HbLo = HbHi + 20480000;
  unsigned short* xlo  = HbHi;
  unsigned short* Sup  = (unsigned short*)alloc(HB);
  unsigned short* Loc  = (unsigned short*)alloc(HB);
  const int WTOT = 512 * 512 + 12 * 512 * 256;
  unsigned short* WtHi = (unsigned short*)alloc((size_t)WTOT * 2);
  unsigned short* WtLo = (unsigned short*)alloc((size_t)WTOT * 2);
  float* sup3    = (float*)alloc((size_t)240000 * 4);
  int*   counts  = (int*)alloc((size_t)2 * NN * 4);   // counts + cursor contiguous
  int*   cursor  = counts + NN;
  int*   rp      = (int*)alloc((size_t)(NN + 1) * 4);
  int*   ci      = (int*)alloc((size_t)E * 4);
  float* vw      = (float*)alloc((size_t)E * 4);
  (void)ws_size; (void)n_in; (void)out_size;

  // CSR build (deterministic: rows sorted by edge id)
  hipMemsetAsync(counts, 0, (size_t)2 * NN * 4, stream);
  k_count<<<(E + 255) / 256, 256, 0, stream>>>(edst, E, counts);
  k_scan<<<1, 1024, 0, stream>>>(counts, rp);
  k_fill<<<(E + 255) / 256, 256, 0, stream>>>(edst, E, rp, cursor, ci);
  k_sort_rows<<<(NN + 255) / 256, 256, 0, stream>>>(rp, ci, vw, esrc, ew);

  // split x -> bf16 hi/lo ; pack transposed weights hi/lo
  k_split<<<(10240000 + 255) / 256, 256, 0, stream>>>((const float4*)x, (ushort4*)xhi, (ushort4*)xlo, 10240000);
  k_pack_w<<<(WTOT + 255) / 256, 256, 0, stream>>>(W_in, LW_in, W_blk, LW_blk, WtHi, WtLo);

  dim3 gg(1250, 2), gb(256);
  // layer 0 (K=512)
  k_gemm_dual<<<gg, gb, 0, stream>>>(xhi, xlo, WtHi, WtLo, Sup, Loc, 512);
  k_agg<<<NN, 256, 0, stream>>>(Sup, Loc, b_in, rp, ci, vw, HaHi, HaLo, carrier, 1);

  const unsigned short* WmHi = WtHi + 512 * 512;
  const unsigned short* WmLo = WtLo + 512 * 512;
  for(int l = 0; l < 6; ++l){
    const int li0 = 2 * l, li1 = 2 * l + 1;
    k_gemm_dual<<<gg, gb, 0, stream>>>(HaHi, HaLo, WmHi + (size_t)li0 * 131072, WmLo + (size_t)li0 * 131072, Sup, Loc, 256);
    k_agg<<<NN, 256, 0, stream>>>(Sup, Loc, b_blk + li0 * 256, rp, ci, vw, HbHi, HbLo, carrier, 0);
    k_gemm_dual<<<gg, gb, 0, stream>>>(HbHi, HbLo, WmHi + (size_t)li1 * 131072, WmLo + (size_t)li1 * 131072, Sup, Loc, 256);
    k_agg<<<NN, 256, 0, stream>>>(Sup, Loc, b_blk + li1 * 256, rp, ci, vw, HaHi, HaLo, carrier, (l == 5) ? 3 : 2);
  }

  // output layer, f32 from carrier
  k_out_sup<<<MROWS / 4, 256, 0, stream>>>(carrier, W_out, sup3);
  k_out_final<<<MROWS / 4, 256, 0, stream>>>(carrier, LW_out, b_out, rp, ci, vw, sup3, xout);
}

// Round 4
// 2165.672 us; speedup vs baseline: 1.4364x; 1.2852x over previous
//
#include <hip/hip_runtime.h>

#define NN 10000
#define BB 8
#define MROWS 80000   // BB*NN

typedef float f32x4 __attribute__((ext_vector_type(4)));
typedef _Float16 f16;
typedef _Float16 f16x8 __attribute__((ext_vector_type(8)));

typedef __attribute__((address_space(1))) void as1_void;
typedef __attribute__((address_space(3))) void as3_void;

static __device__ __forceinline__ void gl_lds16(const void* g, void* l){
  __builtin_amdgcn_global_load_lds((as1_void*)g, (as3_void*)l, 16, 0, 0);
}

// ---------------- CSR build ----------------
__global__ void k_count(const int* __restrict__ dst, int E, int* __restrict__ counts){
  int i = blockIdx.x * blockDim.x + threadIdx.x;
  if(i < E) atomicAdd(&counts[dst[i]], 1);
}

__global__ void k_scan(const int* __restrict__ counts, int* __restrict__ rp){
  __shared__ int buf[1024];
  __shared__ int carry;
  const int t = threadIdx.x;
  if(t == 0){ carry = 0; rp[0] = 0; }
  __syncthreads();
  for(int base = 0; base < NN; base += 1024){
    int v = (base + t < NN) ? counts[base + t] : 0;
    buf[t] = v;
    __syncthreads();
    for(int off = 1; off < 1024; off <<= 1){
      int x = (t >= off) ? buf[t - off] : 0;
      __syncthreads();
      buf[t] += x;
      __syncthreads();
    }
    if(base + t < NN) rp[base + t + 1] = carry + buf[t];
    __syncthreads();
    if(t == 0) carry += buf[1023];
    __syncthreads();
  }
}

__global__ void k_fill(const int* __restrict__ dst, int E, const int* __restrict__ rp,
                       int* __restrict__ cursor, int* __restrict__ ci){
  int i = blockIdx.x * blockDim.x + threadIdx.x;
  if(i < E){
    int d = dst[i];
    int p = rp[d] + atomicAdd(&cursor[d], 1);
    ci[p] = i;   // edge id, sorted deterministically afterwards
  }
}

__global__ void k_sort_rows(const int* __restrict__ rp, int* __restrict__ ci, float* __restrict__ vw,
                            const int* __restrict__ esrc, const float* __restrict__ ew){
  const int n = blockIdx.x * blockDim.x + threadIdx.x;
  if(n >= NN) return;
  const int s = rp[n], e = rp[n + 1];
  for(int i = s; i < e - 1; ++i){           // selection sort by edge id (unique) -> deterministic
    int mj = i, mv = ci[i];
    for(int j = i + 1; j < e; ++j){
      int v = ci[j];
      if(v < mv){ mv = v; mj = j; }
    }
    ci[mj] = ci[i]; ci[i] = mv;
  }
  for(int p = s; p < e; ++p){
    int eid = ci[p];
    ci[p] = esrc[eid];
    vw[p] = ew[eid];
  }
}

// ---------------- f32 -> fp16 convert (8 at a time) ----------------
__global__ void k_cvt(const float4* __restrict__ in, f16x8* __restrict__ out, int n8){
  int i = blockIdx.x * blockDim.x + threadIdx.x;
  if(i >= n8) return;
  float4 v0 = in[2 * i], v1 = in[2 * i + 1];
  f16x8 o;
  o[0] = (f16)v0.x; o[1] = (f16)v0.y; o[2] = (f16)v0.z; o[3] = (f16)v0.w;
  o[4] = (f16)v1.x; o[5] = (f16)v1.y; o[6] = (f16)v1.z; o[7] = (f16)v1.w;
  out[i] = o;
}

// Pack weights transposed to fp16: Wt[c][k] = W[k][c].
// layout: [0, 512*512): layer0 (K=512, cols 0..255 = W_in, 256..511 = LW_in)
//         then 12 x [512][256] for W_blk/LW_blk
__global__ void k_pack_w(const float* __restrict__ Wi, const float* __restrict__ LWi,
                         const float* __restrict__ Wb, const float* __restrict__ LWb,
                         f16* __restrict__ dh){
  const int T0 = 512 * 512;
  const int TOT = T0 + 12 * 512 * 256;
  int i = blockIdx.x * blockDim.x + threadIdx.x;
  if(i >= TOT) return;
  float v;
  if(i < T0){
    int c = i >> 9, k = i & 511;
    v = (c < 256) ? Wi[k * 256 + c] : LWi[k * 256 + (c - 256)];
  } else {
    int j = i - T0;
    int li = j >> 17;          // 512*256 = 2^17
    int r = j & 131071;
    int c = r >> 8, k = r & 255;
    const float* src = (c < 256) ? (Wb + (size_t)li * 65536) : (LWb + (size_t)li * 65536);
    v = src[k * 256 + (c & 255)];
  }
  dh[i] = (f16)v;
}

// ---------------- dual GEMM (fp16): by=0 -> Sup, by=1 -> Loc
// A: [80000, K] fp16,  Bt: [512, K] fp16 (row = output col)
// BM=64, BN=256, BK=32. 2-phase pipeline (counted vmcnt(5)), LDS 40KB dbuf
// -> 4 blocks/CU. XCD-pair swizzle: logical (m,by) pairs adjacent on the
// same XCD so by=1 reads A from that XCD's L2 (bijective m204 mapping).
// Bank-conflict-free via both-sides chunk XOR (verified 0 conflicts in R3).
__global__ __launch_bounds__(256) void k_gemm_dual(
    const f16* __restrict__ A, const f16* __restrict__ Bt,
    f16* __restrict__ Sup, f16* __restrict__ Loc, int K, int nblk)
{
  __shared__ f16 As[2][2048];   // 2 x 4 KB  (64 rows x 32 k)
  __shared__ f16 Bs[2][8192];   // 2 x 16 KB (256 rows x 32 k)
  const int t = threadIdx.x;
  // XCD-aware bijective remap: hardware xcd = pid % 8
  const int pid = blockIdx.x;
  const int q = nblk >> 3, r = nblk & 7;
  const int xcd = pid & 7, sl = pid >> 3;
  const int wg = (xcd < r ? xcd * (q + 1) : r * (q + 1) + (xcd - r) * q) + sl;
  const int m0 = (wg >> 1) << 6;
  const int by = wg & 1;
  const int n0 = by << 8;
  const int lane = t & 63, wv = t >> 6;
  const int rA = lane & 15, g = lane >> 4;
  f32x4 acc[4][4] = {};
  const int nsteps = K >> 5;
  const int rowt = t >> 2;                         // 0..63
  const int csw  = (t & 3) ^ ((rowt >> 1) & 3);    // pre-swizzled source chunk
  const int cbt  = csw << 3;                       // f16 offset 0/8/16/24

  // ---- staging: 5 x gl_lds16 per thread per K-step ----
  auto STAGE = [&](int s, int buf){
    const int k0 = s << 5;
    const size_t aoff = (size_t)(m0 + rowt) * K + k0 + cbt;
    gl_lds16(A + aoff, (char*)As[buf] + t * 16);
    #pragma unroll
    for(int qq = 0; qq < 4; ++qq){
      const size_t boff = (size_t)(n0 + qq * 64 + rowt) * K + k0 + cbt;
      gl_lds16(Bt + boff, (char*)Bs[buf] + qq * 4096 + t * 16);
    }
  };

  STAGE(0, 0);
  int cur = 0;
  const int slotx = (rA >> 1) & 3;        // read-side XOR base

  for(int s = 0; s < nsteps; ++s){
    __builtin_amdgcn_sched_barrier(0);
    if(s + 1 < nsteps){
      STAGE(s + 1, cur ^ 1);
      asm volatile("s_waitcnt vmcnt(5)" ::: "memory");  // cur's 5 done, next 5 in flight
    } else {
      asm volatile("s_waitcnt vmcnt(0)" ::: "memory");
    }
    __builtin_amdgcn_s_barrier();
    __builtin_amdgcn_sched_barrier(0);

    f16x8 av[4], bv[4];
    #pragma unroll
    for(int mi = 0; mi < 4; ++mi){
      const int ao = (mi * 16 + rA) * 32 + ((g ^ slotx) << 3);
      av[mi] = *(const f16x8*)(As[cur] + ao);
    }
    #pragma unroll
    for(int ni = 0; ni < 4; ++ni){
      const int bo = wv * 2048 + (ni * 16 + rA) * 32 + ((g ^ slotx) << 3);
      bv[ni] = *(const f16x8*)(Bs[cur] + bo);
    }
    #pragma unroll
    for(int mi = 0; mi < 4; ++mi){
      #pragma unroll
      for(int ni = 0; ni < 4; ++ni){
        acc[mi][ni] = __builtin_amdgcn_mfma_f32_16x16x32_f16(av[mi], bv[ni], acc[mi][ni], 0, 0, 0);
      }
    }
    __builtin_amdgcn_sched_barrier(0);
    __builtin_amdgcn_s_barrier();     // all waves done reading cur before restage
    cur ^= 1;
  }

  f16* dst = (by == 0) ? Sup : Loc;
  const int wn = wv << 6;
  #pragma unroll
  for(int mi = 0; mi < 4; ++mi){
    const int rowb = m0 + mi * 16 + g * 4;
    #pragma unroll
    for(int ni = 0; ni < 4; ++ni){
      const int col = wn + ni * 16 + rA;
      #pragma unroll
      for(int r2 = 0; r2 < 4; ++r2){
        dst[(size_t)(rowb + r2) * 256 + col] = (f16)acc[mi][ni][r2];
      }
    }
  }
}

// ---------------- aggregation + local + bias (+residual) ----------------
// mode 0: Hnext only
// mode 1: carrier = t; Hnext
// mode 2: carrier = (carrier + t)*0.5; Hnext
// mode 3: carrier = (carrier + t)*0.5; NO Hnext (last layer)
__global__ __launch_bounds__(256) void k_agg(
    const f16* __restrict__ Sup, const f16* __restrict__ Loc,
    const float* __restrict__ bias,
    const int* __restrict__ rp, const int* __restrict__ ci, const float* __restrict__ vw,
    f16* __restrict__ Hn, float* __restrict__ carrier, const int mode)
{
  const int n = blockIdx.x;
  const int t = threadIdx.x;
  const int b = t >> 5;
  const int d0 = (t & 31) << 3;
  const size_t rowbase = ((size_t)b * NN + n) * 256 + d0;
  float a[8];
  {
    const f16x8 lv = *(const f16x8*)(Loc + rowbase);
    float4 q0 = *(const float4*)(bias + d0);
    float4 q1 = *(const float4*)(bias + d0 + 4);
    a[0] = (float)lv[0] + q0.x; a[1] = (float)lv[1] + q0.y;
    a[2] = (float)lv[2] + q0.z; a[3] = (float)lv[3] + q0.w;
    a[4] = (float)lv[4] + q1.x; a[5] = (float)lv[5] + q1.y;
    a[6] = (float)lv[6] + q1.z; a[7] = (float)lv[7] + q1.w;
  }
  const int s = rp[n], e = rp[n + 1];
  const size_t bb = (size_t)b * NN * 256 + d0;
  for(int i = s; i < e; ++i){
    const int src = ci[i];
    const float w = vw[i];
    const f16x8 sv = *(const f16x8*)(Sup + bb + (size_t)src * 256);
    a[0] = fmaf(w, (float)sv[0], a[0]);
    a[1] = fmaf(w, (float)sv[1], a[1]);
    a[2] = fmaf(w, (float)sv[2], a[2]);
    a[3] = fmaf(w, (float)sv[3], a[3]);
    a[4] = fmaf(w, (float)sv[4], a[4]);
    a[5] = fmaf(w, (float)sv[5], a[5]);
    a[6] = fmaf(w, (float)sv[6], a[6]);
    a[7] = fmaf(w, (float)sv[7], a[7]);
  }
  if(mode >= 2){
    float4 c0 = *(const float4*)(carrier + rowbase);
    float4 c1 = *(const float4*)(carrier + rowbase + 4);
    a[0] = (a[0] + c0.x) * 0.5f; a[1] = (a[1] + c0.y) * 0.5f;
    a[2] = (a[2] + c0.z) * 0.5f; a[3] = (a[3] + c0.w) * 0.5f;
    a[4] = (a[4] + c1.x) * 0.5f; a[5] = (a[5] + c1.y) * 0.5f;
    a[6] = (a[6] + c1.z) * 0.5f; a[7] = (a[7] + c1.w) * 0.5f;
  }
  if(mode){
    *(float4*)(carrier + rowbase)     = make_float4(a[0], a[1], a[2], a[3]);
    *(float4*)(carrier + rowbase + 4) = make_float4(a[4], a[5], a[6], a[7]);
  }
  if(mode == 3) return;
  f16x8 o;
  #pragma unroll
  for(int j = 0; j < 8; ++j) o[j] = (f16)a[j];
  *(f16x8*)(Hn + rowbase) = o;
}

// ---------------- output layer (Dout=3), f32 throughout ----------------
__global__ __launch_bounds__(256) void k_out_sup(const float* __restrict__ h,
    const float* __restrict__ Wo, float* __restrict__ sup3){
  const int gid = blockIdx.x * 4 + (threadIdx.x >> 6);
  const int lane = threadIdx.x & 63;
  if(gid >= MROWS) return;
  const float4 v = *(const float4*)(h + (size_t)gid * 256 + lane * 4);
  const float hv[4] = {v.x, v.y, v.z, v.w};
  float p0 = 0.f, p1 = 0.f, p2 = 0.f;
  #pragma unroll
  for(int j = 0; j < 4; ++j){
    const int k = lane * 4 + j;
    p0 = fmaf(hv[j], Wo[k * 3 + 0], p0);
    p1 = fmaf(hv[j], Wo[k * 3 + 1], p1);
    p2 = fmaf(hv[j], Wo[k * 3 + 2], p2);
  }
  #pragma unroll
  for(int off = 32; off; off >>= 1){
    p0 += __shfl_xor(p0, off, 64);
    p1 += __shfl_xor(p1, off, 64);
    p2 += __shfl_xor(p2, off, 64);
  }
  if(lane == 0){
    float* o = sup3 + (size_t)gid * 3;
    o[0] = p0; o[1] = p1; o[2] = p2;
  }
}

__global__ __launch_bounds__(256) void k_out_final(const float* __restrict__ h,
    const float* __restrict__ LWo, const float* __restrict__ bo,
    const int* __restrict__ rp, const int* __restrict__ ci, const float* __restrict__ vw,
    const float* __restrict__ sup3, float* __restrict__ out){
  const int gid = blockIdx.x * 4 + (threadIdx.x >> 6);
  const int lane = threadIdx.x & 63;
  if(gid >= MROWS) return;
  const int b = gid / NN, n = gid % NN;
  const float4 v = *(const float4*)(h + (size_t)gid * 256 + lane * 4);
  const float hv[4] = {v.x, v.y, v.z, v.w};
  float p0 = 0.f, p1 = 0.f, p2 = 0.f;
  #pragma unroll
  for(int j = 0; j < 4; ++j){
    const int k = lane * 4 + j;
    p0 = fmaf(hv[j], LWo[k * 3 + 0], p0);
    p1 = fmaf(hv[j], LWo[k * 3 + 1], p1);
    p2 = fmaf(hv[j], LWo[k * 3 + 2], p2);
  }
  const int s = rp[n], e = rp[n + 1];
  for(int i = s + lane; i < e; i += 64){
    const int src = ci[i];
    const float w = vw[i];
    const float* sp = sup3 + ((size_t)b * NN + src) * 3;
    p0 = fmaf(w, sp[0], p0);
    p1 = fmaf(w, sp[1], p1);
    p2 = fmaf(w, sp[2], p2);
  }
  #pragma unroll
  for(int off = 32; off; off >>= 1){
    p0 += __shfl_xor(p0, off, 64);
    p1 += __shfl_xor(p1, off, 64);
    p2 += __shfl_xor(p2, off, 64);
  }
  if(lane == 0){
    float* o = out + (size_t)gid * 3;
    o[0] = p0 + bo[0]; o[1] = p1 + bo[1]; o[2] = p2 + bo[2];
  }
}

// ---------------- host ----------------
extern "C" void kernel_launch(void* const* d_in, const int* in_sizes, int n_in,
                              void* d_out, int out_size, void* d_ws, size_t ws_size,
                              hipStream_t stream) {
  const float* x     = (const float*)d_in[0];
  const int*   esrc  = (const int*)d_in[1];
  const int*   edst  = (const int*)d_in[2];
  const float* ew    = (const float*)d_in[3];
  const float* W_in  = (const float*)d_in[4];
  const float* LW_in = (const float*)d_in[5];
  const float* b_in  = (const float*)d_in[6];
  const float* W_blk = (const float*)d_in[7];
  const float* LW_blk= (const float*)d_in[8];
  const float* b_blk = (const float*)d_in[9];
  const float* W_out = (const float*)d_in[10];
  const float* LW_out= (const float*)d_in[11];
  const float* b_out = (const float*)d_in[12];
  const int E = in_sizes[1];

  float* outF    = (float*)d_out;
  float* xout    = outF;                 // [B,N,3]
  float* carrier = outF + 240000;        // h region [B,N,256] f32; doubles as x16 scratch pre-layer0
  f16* x16 = (f16*)carrier;              // 40.96M fp16 = exactly the h region (81.92MB)

  char* ws = (char*)d_ws;
  size_t off = 0;
  auto alloc = [&](size_t bytes) -> char* {
    char* p = ws + off;
    off += (bytes + 255) & ~(size_t)255;
    return p;
  };
  const size_t HB = (size_t)20480000 * 2;           // one fp16 activation buffer
  f16* Ha  = (f16*)alloc(HB);
  f16* Hb  = (f16*)alloc(HB);
  f16* Sup = (f16*)alloc(HB);
  f16* Loc = (f16*)alloc(HB);
  const int WTOT = 512 * 512 + 12 * 512 * 256;
  f16* Wt = (f16*)alloc((size_t)WTOT * 2);
  float* sup3    = (float*)alloc((size_t)240000 * 4);
  int*   counts  = (int*)alloc((size_t)2 * NN * 4);   // counts + cursor contiguous
  int*   cursor  = counts + NN;
  int*   rp      = (int*)alloc((size_t)(NN + 1) * 4);
  int*   ci      = (int*)alloc((size_t)E * 4);
  float* vw      = (float*)alloc((size_t)E * 4);
  (void)ws_size; (void)n_in; (void)out_size;

  // CSR build (deterministic: rows sorted by edge id)
  hipMemsetAsync(counts, 0, (size_t)2 * NN * 4, stream);
  k_count<<<(E + 255) / 256, 256, 0, stream>>>(edst, E, counts);
  k_scan<<<1, 1024, 0, stream>>>(counts, rp);
  k_fill<<<(E + 255) / 256, 256, 0, stream>>>(edst, E, rp, cursor, ci);
  k_sort_rows<<<(NN + 255) / 256, 256, 0, stream>>>(rp, ci, vw, esrc, ew);

  // convert x -> fp16 ; pack transposed weights fp16
  k_cvt<<<(5120000 + 255) / 256, 256, 0, stream>>>((const float4*)x, (f16x8*)x16, 5120000);
  k_pack_w<<<(WTOT + 255) / 256, 256, 0, stream>>>(W_in, LW_in, W_blk, LW_blk, Wt);

  const int NBLK = 2500;   // 1250 m-blocks x 2 (Sup/Loc)
  // layer 0 (K=512)
  k_gemm_dual<<<NBLK, 256, 0, stream>>>(x16, Wt, Sup, Loc, 512, NBLK);
  k_agg<<<NN, 256, 0, stream>>>(Sup, Loc, b_in, rp, ci, vw, Ha, carrier, 1);

  const f16* Wm = Wt + 512 * 512;
  for(int l = 0; l < 6; ++l){
    const int li0 = 2 * l, li1 = 2 * l + 1;
    k_gemm_dual<<<NBLK, 256, 0, stream>>>(Ha, Wm + (size_t)li0 * 131072, Sup, Loc, 256, NBLK);
    k_agg<<<NN, 256, 0, stream>>>(Sup, Loc, b_blk + li0 * 256, rp, ci, vw, Hb, carrier, 0);
    k_gemm_dual<<<NBLK, 256, 0, stream>>>(Hb, Wm + (size_t)li1 * 131072, Sup, Loc, 256, NBLK);
    k_agg<<<NN, 256, 0, stream>>>(Sup, Loc, b_blk + li1 * 256, rp, ci, vw, Ha, carrier, (l == 5) ? 3 : 2);
  }

  // output layer, f32 from carrier
  k_out_sup<<<MROWS / 4, 256, 0, stream>>>(carrier, W_out, sup3);
  k_out_final<<<MROWS / 4, 256, 0, stream>>>(carrier, LW_out, b_out, rp, ci, vw, sup3, xout);
}

// Round 5
// 1743.028 us; speedup vs baseline: 1.7847x; 1.2425x over previous
//
#include <hip/hip_runtime.h>

#define NN 10000
#define BB 8
#define MROWS 80000   // BB*NN

typedef float f32x4 __attribute__((ext_vector_type(4)));
typedef _Float16 f16;
typedef _Float16 f16x8 __attribute__((ext_vector_type(8)));

typedef __attribute__((address_space(1))) void as1_void;
typedef __attribute__((address_space(3))) void as3_void;

static __device__ __forceinline__ void gl_lds16(const void* g, void* l){
  __builtin_amdgcn_global_load_lds((as1_void*)g, (as3_void*)l, 16, 0, 0);
}

// ---------------- CSR build ----------------
__global__ void k_count(const int* __restrict__ dst, int E, int* __restrict__ counts){
  int i = blockIdx.x * blockDim.x + threadIdx.x;
  if(i < E) atomicAdd(&counts[dst[i]], 1);
}

__global__ void k_scan(const int* __restrict__ counts, int* __restrict__ rp){
  __shared__ int buf[1024];
  __shared__ int carry;
  const int t = threadIdx.x;
  if(t == 0){ carry = 0; rp[0] = 0; }
  __syncthreads();
  for(int base = 0; base < NN; base += 1024){
    int v = (base + t < NN) ? counts[base + t] : 0;
    buf[t] = v;
    __syncthreads();
    for(int off = 1; off < 1024; off <<= 1){
      int x = (t >= off) ? buf[t - off] : 0;
      __syncthreads();
      buf[t] += x;
      __syncthreads();
    }
    if(base + t < NN) rp[base + t + 1] = carry + buf[t];
    __syncthreads();
    if(t == 0) carry += buf[1023];
    __syncthreads();
  }
}

__global__ void k_fill(const int* __restrict__ dst, int E, const int* __restrict__ rp,
                       int* __restrict__ cursor, int* __restrict__ ci){
  int i = blockIdx.x * blockDim.x + threadIdx.x;
  if(i < E){
    int d = dst[i];
    int p = rp[d] + atomicAdd(&cursor[d], 1);
    ci[p] = i;   // edge id, sorted deterministically afterwards
  }
}

__global__ void k_sort_rows(const int* __restrict__ rp, int* __restrict__ ci, float* __restrict__ vw,
                            const int* __restrict__ esrc, const float* __restrict__ ew){
  const int n = blockIdx.x * blockDim.x + threadIdx.x;
  if(n >= NN) return;
  const int s = rp[n], e = rp[n + 1];
  for(int i = s; i < e - 1; ++i){           // selection sort by edge id (unique) -> deterministic
    int mj = i, mv = ci[i];
    for(int j = i + 1; j < e; ++j){
      int v = ci[j];
      if(v < mv){ mv = v; mj = j; }
    }
    ci[mj] = ci[i]; ci[i] = mv;
  }
  for(int p = s; p < e; ++p){
    int eid = ci[p];
    ci[p] = esrc[eid];
    vw[p] = ew[eid];
  }
}

// ---------------- f32 -> fp16 convert (8 at a time) ----------------
__global__ void k_cvt(const float4* __restrict__ in, f16x8* __restrict__ out, int n8){
  int i = blockIdx.x * blockDim.x + threadIdx.x;
  if(i >= n8) return;
  float4 v0 = in[2 * i], v1 = in[2 * i + 1];
  f16x8 o;
  o[0] = (f16)v0.x; o[1] = (f16)v0.y; o[2] = (f16)v0.z; o[3] = (f16)v0.w;
  o[4] = (f16)v1.x; o[5] = (f16)v1.y; o[6] = (f16)v1.z; o[7] = (f16)v1.w;
  out[i] = o;
}

// Pack weights transposed to fp16: Wt[c][k] = W[k][c].
__global__ void k_pack_w(const float* __restrict__ Wi, const float* __restrict__ LWi,
                         const float* __restrict__ Wb, const float* __restrict__ LWb,
                         f16* __restrict__ dh){
  const int T0 = 512 * 512;
  const int TOT = T0 + 12 * 512 * 256;
  int i = blockIdx.x * blockDim.x + threadIdx.x;
  if(i >= TOT) return;
  float v;
  if(i < T0){
    int c = i >> 9, k = i & 511;
    v = (c < 256) ? Wi[k * 256 + c] : LWi[k * 256 + (c - 256)];
  } else {
    int j = i - T0;
    int li = j >> 17;          // 512*256 = 2^17
    int r = j & 131071;
    int c = r >> 8, k = r & 255;
    const float* src = (c < 256) ? (Wb + (size_t)li * 65536) : (LWb + (size_t)li * 65536);
    v = src[k * 256 + (c & 255)];
  }
  dh[i] = (f16)v;
}

// ---------------- dual GEMM (fp16): by=0 -> Sup, by=1 -> Loc (unchanged from R4) ----
__global__ __launch_bounds__(256) void k_gemm_dual(
    const f16* __restrict__ A, const f16* __restrict__ Bt,
    f16* __restrict__ Sup, f16* __restrict__ Loc, int K, int nblk)
{
  __shared__ f16 As[2][2048];   // 2 x 4 KB  (64 rows x 32 k)
  __shared__ f16 Bs[2][8192];   // 2 x 16 KB (256 rows x 32 k)
  const int t = threadIdx.x;
  const int pid = blockIdx.x;
  const int q = nblk >> 3, r = nblk & 7;
  const int xcd = pid & 7, sl = pid >> 3;
  const int wg = (xcd < r ? xcd * (q + 1) : r * (q + 1) + (xcd - r) * q) + sl;
  const int m0 = (wg >> 1) << 6;
  const int by = wg & 1;
  const int n0 = by << 8;
  const int lane = t & 63, wv = t >> 6;
  const int rA = lane & 15, g = lane >> 4;
  f32x4 acc[4][4] = {};
  const int nsteps = K >> 5;
  const int rowt = t >> 2;                         // 0..63
  const int csw  = (t & 3) ^ ((rowt >> 1) & 3);    // pre-swizzled source chunk
  const int cbt  = csw << 3;                       // f16 offset 0/8/16/24

  auto STAGE = [&](int s, int buf){
    const int k0 = s << 5;
    const size_t aoff = (size_t)(m0 + rowt) * K + k0 + cbt;
    gl_lds16(A + aoff, (char*)As[buf] + t * 16);
    #pragma unroll
    for(int qq = 0; qq < 4; ++qq){
      const size_t boff = (size_t)(n0 + qq * 64 + rowt) * K + k0 + cbt;
      gl_lds16(Bt + boff, (char*)Bs[buf] + qq * 4096 + t * 16);
    }
  };

  STAGE(0, 0);
  int cur = 0;
  const int slotx = (rA >> 1) & 3;        // read-side XOR base

  for(int s = 0; s < nsteps; ++s){
    __builtin_amdgcn_sched_barrier(0);
    if(s + 1 < nsteps){
      STAGE(s + 1, cur ^ 1);
      asm volatile("s_waitcnt vmcnt(5)" ::: "memory");
    } else {
      asm volatile("s_waitcnt vmcnt(0)" ::: "memory");
    }
    __builtin_amdgcn_s_barrier();
    __builtin_amdgcn_sched_barrier(0);

    f16x8 av[4], bv[4];
    #pragma unroll
    for(int mi = 0; mi < 4; ++mi){
      const int ao = (mi * 16 + rA) * 32 + ((g ^ slotx) << 3);
      av[mi] = *(const f16x8*)(As[cur] + ao);
    }
    #pragma unroll
    for(int ni = 0; ni < 4; ++ni){
      const int bo = wv * 2048 + (ni * 16 + rA) * 32 + ((g ^ slotx) << 3);
      bv[ni] = *(const f16x8*)(Bs[cur] + bo);
    }
    #pragma unroll
    for(int mi = 0; mi < 4; ++mi){
      #pragma unroll
      for(int ni = 0; ni < 4; ++ni){
        acc[mi][ni] = __builtin_amdgcn_mfma_f32_16x16x32_f16(av[mi], bv[ni], acc[mi][ni], 0, 0, 0);
      }
    }
    __builtin_amdgcn_sched_barrier(0);
    __builtin_amdgcn_s_barrier();
    cur ^= 1;
  }

  f16* dst = (by == 0) ? Sup : Loc;
  const int wn = wv << 6;
  #pragma unroll
  for(int mi = 0; mi < 4; ++mi){
    const int rowb = m0 + mi * 16 + g * 4;
    #pragma unroll
    for(int ni = 0; ni < 4; ++ni){
      const int col = wn + ni * 16 + rA;
      #pragma unroll
      for(int r2 = 0; r2 < 4; ++r2){
        dst[(size_t)(rowb + r2) * 256 + col] = (f16)acc[mi][ni][r2];
      }
    }
  }
}

// ---------------- aggregation, XCD-batch-pinned, D-split two halves ----------------
// grid = 10000 blocks: pid<5000 -> d-half 0, else half 1; batch = pid%8
// (round-robin -> all blocks of batch b on XCD b; (batch,half) gather
//  working set = 10000*256B = 2.56MB < 4MB L2). 16 dst nodes per block,
//  16 lanes per node, 8 dims per lane.
// mode 0: Hnext = fp16(t)
// mode 2: Hnext = fp16((Hprev + t)*0.5)   (Hprev may alias Hnext, in-place)
// mode 3: hout(f32) = (Hprev + t)*0.5     (no fp16 write; last layer)
__global__ __launch_bounds__(256) void k_agg(
    const f16* __restrict__ Sup, const f16* __restrict__ Loc,
    const float* __restrict__ bias,
    const int* __restrict__ rp, const int* __restrict__ ci, const float* __restrict__ vw,
    const f16* __restrict__ Hprev, f16* __restrict__ Hnext,
    float* __restrict__ hout, const int mode)
{
  const int pid = blockIdx.x;
  const int half = (pid >= 5000) ? 1 : 0;
  const int rem = pid - half * 5000;
  const int b = rem & 7;
  const int grp = rem >> 3;               // 0..624
  const int t = threadIdx.x;
  const int j = t >> 4;                   // node within group (0..15)
  const int tt = t & 15;
  const int n = grp * 16 + j;
  const int d0 = half * 128 + tt * 8;
  const size_t rowbase = ((size_t)b * NN + n) * 256 + d0;
  float a[8];
  {
    const f16x8 lv = *(const f16x8*)(Loc + rowbase);
    float4 q0 = *(const float4*)(bias + d0);
    float4 q1 = *(const float4*)(bias + d0 + 4);
    a[0] = (float)lv[0] + q0.x; a[1] = (float)lv[1] + q0.y;
    a[2] = (float)lv[2] + q0.z; a[3] = (float)lv[3] + q0.w;
    a[4] = (float)lv[4] + q1.x; a[5] = (float)lv[5] + q1.y;
    a[6] = (float)lv[6] + q1.z; a[7] = (float)lv[7] + q1.w;
  }
  const int s = rp[n], e = rp[n + 1];
  const size_t bb = (size_t)b * NN * 256 + d0;
  for(int i = s; i < e; ++i){
    const int src = ci[i];
    const float w = vw[i];
    const f16x8 sv = *(const f16x8*)(Sup + bb + (size_t)src * 256);
    a[0] = fmaf(w, (float)sv[0], a[0]);
    a[1] = fmaf(w, (float)sv[1], a[1]);
    a[2] = fmaf(w, (float)sv[2], a[2]);
    a[3] = fmaf(w, (float)sv[3], a[3]);
    a[4] = fmaf(w, (float)sv[4], a[4]);
    a[5] = fmaf(w, (float)sv[5], a[5]);
    a[6] = fmaf(w, (float)sv[6], a[6]);
    a[7] = fmaf(w, (float)sv[7], a[7]);
  }
  if(mode >= 2){
    const f16x8 hp = *(const f16x8*)(Hprev + rowbase);
    #pragma unroll
    for(int k = 0; k < 8; ++k) a[k] = (a[k] + (float)hp[k]) * 0.5f;
  }
  if(mode == 3){
    *(float4*)(hout + rowbase)     = make_float4(a[0], a[1], a[2], a[3]);
    *(float4*)(hout + rowbase + 4) = make_float4(a[4], a[5], a[6], a[7]);
    return;
  }
  f16x8 o;
  #pragma unroll
  for(int k = 0; k < 8; ++k) o[k] = (f16)a[k];
  *(f16x8*)(Hnext + rowbase) = o;
}

// ---------------- output layer (Dout=3), f32 throughout ----------------
__global__ __launch_bounds__(256) void k_out_sup(const float* __restrict__ h,
    const float* __restrict__ Wo, float* __restrict__ sup3){
  const int gid = blockIdx.x * 4 + (threadIdx.x >> 6);
  const int lane = threadIdx.x & 63;
  if(gid >= MROWS) return;
  const float4 v = *(const float4*)(h + (size_t)gid * 256 + lane * 4);
  const float hv[4] = {v.x, v.y, v.z, v.w};
  float p0 = 0.f, p1 = 0.f, p2 = 0.f;
  #pragma unroll
  for(int j = 0; j < 4; ++j){
    const int k = lane * 4 + j;
    p0 = fmaf(hv[j], Wo[k * 3 + 0], p0);
    p1 = fmaf(hv[j], Wo[k * 3 + 1], p1);
    p2 = fmaf(hv[j], Wo[k * 3 + 2], p2);
  }
  #pragma unroll
  for(int off = 32; off; off >>= 1){
    p0 += __shfl_xor(p0, off, 64);
    p1 += __shfl_xor(p1, off, 64);
    p2 += __shfl_xor(p2, off, 64);
  }
  if(lane == 0){
    float* o = sup3 + (size_t)gid * 3;
    o[0] = p0; o[1] = p1; o[2] = p2;
  }
}

__global__ __launch_bounds__(256) void k_out_final(const float* __restrict__ h,
    const float* __restrict__ LWo, const float* __restrict__ bo,
    const int* __restrict__ rp, const int* __restrict__ ci, const float* __restrict__ vw,
    const float* __restrict__ sup3, float* __restrict__ out){
  const int gid = blockIdx.x * 4 + (threadIdx.x >> 6);
  const int lane = threadIdx.x & 63;
  if(gid >= MROWS) return;
  const int b = gid / NN, n = gid % NN;
  const float4 v = *(const float4*)(h + (size_t)gid * 256 + lane * 4);
  const float hv[4] = {v.x, v.y, v.z, v.w};
  float p0 = 0.f, p1 = 0.f, p2 = 0.f;
  #pragma unroll
  for(int j = 0; j < 4; ++j){
    const int k = lane * 4 + j;
    p0 = fmaf(hv[j], LWo[k * 3 + 0], p0);
    p1 = fmaf(hv[j], LWo[k * 3 + 1], p1);
    p2 = fmaf(hv[j], LWo[k * 3 + 2], p2);
  }
  const int s = rp[n], e = rp[n + 1];
  for(int i = s + lane; i < e; i += 64){
    const int src = ci[i];
    const float w = vw[i];
    const float* sp = sup3 + ((size_t)b * NN + src) * 3;
    p0 = fmaf(w, sp[0], p0);
    p1 = fmaf(w, sp[1], p1);
    p2 = fmaf(w, sp[2], p2);
  }
  #pragma unroll
  for(int off = 32; off; off >>= 1){
    p0 += __shfl_xor(p0, off, 64);
    p1 += __shfl_xor(p1, off, 64);
    p2 += __shfl_xor(p2, off, 64);
  }
  if(lane == 0){
    float* o = out + (size_t)gid * 3;
    o[0] = p0 + bo[0]; o[1] = p1 + bo[1]; o[2] = p2 + bo[2];
  }
}

// ---------------- host ----------------
extern "C" void kernel_launch(void* const* d_in, const int* in_sizes, int n_in,
                              void* d_out, int out_size, void* d_ws, size_t ws_size,
                              hipStream_t stream) {
  const float* x     = (const float*)d_in[0];
  const int*   esrc  = (const int*)d_in[1];
  const int*   edst  = (const int*)d_in[2];
  const float* ew    = (const float*)d_in[3];
  const float* W_in  = (const float*)d_in[4];
  const float* LW_in = (const float*)d_in[5];
  const float* b_in  = (const float*)d_in[6];
  const float* W_blk = (const float*)d_in[7];
  const float* LW_blk= (const float*)d_in[8];
  const float* b_blk = (const float*)d_in[9];
  const float* W_out = (const float*)d_in[10];
  const float* LW_out= (const float*)d_in[11];
  const float* b_out = (const float*)d_in[12];
  const int E = in_sizes[1];

  float* outF  = (float*)d_out;
  float* xout  = outF;                  // [B,N,3]
  float* hOut  = outF + 240000;         // h region [B,N,256] f32, written at last layer
  f16* x16 = (f16*)hOut;                // doubles as fp16-x scratch before layer 0

  char* ws = (char*)d_ws;
  size_t off = 0;
  auto alloc = [&](size_t bytes) -> char* {
    char* p = ws + off;
    off += (bytes + 255) & ~(size_t)255;
    return p;
  };
  const size_t HB = (size_t)20480000 * 2;           // one fp16 activation buffer
  f16* Ha  = (f16*)alloc(HB);
  f16* Hb  = (f16*)alloc(HB);
  f16* Sup = (f16*)alloc(HB);
  f16* Loc = (f16*)alloc(HB);
  const int WTOT = 512 * 512 + 12 * 512 * 256;
  f16* Wt = (f16*)alloc((size_t)WTOT * 2);
  float* sup3    = (float*)alloc((size_t)240000 * 4);
  int*   counts  = (int*)alloc((size_t)2 * NN * 4);   // counts + cursor contiguous
  int*   cursor  = counts + NN;
  int*   rp      = (int*)alloc((size_t)(NN + 1) * 4);
  int*   ci      = (int*)alloc((size_t)E * 4);
  float* vw      = (float*)alloc((size_t)E * 4);
  (void)ws_size; (void)n_in; (void)out_size;

  // CSR build (deterministic: rows sorted by edge id)
  hipMemsetAsync(counts, 0, (size_t)2 * NN * 4, stream);
  k_count<<<(E + 255) / 256, 256, 0, stream>>>(edst, E, counts);
  k_scan<<<1, 1024, 0, stream>>>(counts, rp);
  k_fill<<<(E + 255) / 256, 256, 0, stream>>>(edst, E, rp, cursor, ci);
  k_sort_rows<<<(NN + 255) / 256, 256, 0, stream>>>(rp, ci, vw, esrc, ew);

  // convert x -> fp16 ; pack transposed weights fp16
  k_cvt<<<(5120000 + 255) / 256, 256, 0, stream>>>((const float4*)x, (f16x8*)x16, 5120000);
  k_pack_w<<<(WTOT + 255) / 256, 256, 0, stream>>>(W_in, LW_in, W_blk, LW_blk, Wt);

  const int NBLK = 2500;    // GEMM: 1250 m-blocks x 2 (Sup/Loc)
  const int ABLK = 10000;   // agg: 2 halves x 8 batches x 625 groups
  // layer 0 (K=512): h0 = t
  k_gemm_dual<<<NBLK, 256, 0, stream>>>(x16, Wt, Sup, Loc, 512, NBLK);
  k_agg<<<ABLK, 256, 0, stream>>>(Sup, Loc, b_in, rp, ci, vw, Ha, Ha, xout, 0);

  const f16* Wm = Wt + 512 * 512;
  for(int l = 0; l < 6; ++l){
    const int li0 = 2 * l, li1 = 2 * l + 1;
    k_gemm_dual<<<NBLK, 256, 0, stream>>>(Ha, Wm + (size_t)li0 * 131072, Sup, Loc, 256, NBLK);
    k_agg<<<ABLK, 256, 0, stream>>>(Sup, Loc, b_blk + li0 * 256, rp, ci, vw, Ha, Hb, xout, 0);
    k_gemm_dual<<<NBLK, 256, 0, stream>>>(Hb, Wm + (size_t)li1 * 131072, Sup, Loc, 256, NBLK);
    k_agg<<<ABLK, 256, 0, stream>>>(Sup, Loc, b_blk + li1 * 256, rp, ci, vw, Ha, Ha, hOut, (l == 5) ? 3 : 2);
  }

  // output layer, f32 from hOut (d_out h region)
  k_out_sup<<<MROWS / 4, 256, 0, stream>>>(hOut, W_out, sup3);
  k_out_final<<<MROWS / 4, 256, 0, stream>>>(hOut, LW_out, b_out, rp, ci, vw, sup3, xout);
}